// Round 3
// baseline (32146.594 us; speedup 1.0000x reference)
//
#include <hip/hip_runtime.h>
#include <hip/hip_bf16.h>
#include <math.h>
#include <stdint.h>

#define TT 256
#define BB 128
#define XX 128
#define YY 256
#define HH 512
#define ZZ 256
#define DD 8
#define G3 1536
#define CH 8    // loss-pass t-chunk
#define TC 32   // GRU / scan t-chunk

typedef unsigned int u32;

// ---------------- JAX threefry2x32 PRNG ----------------
__device__ __forceinline__ uint2 tf2(uint2 key, u32 c0, u32 c1) {
  u32 ks0 = key.x, ks1 = key.y, ks2 = ks0 ^ ks1 ^ 0x1BD11BDAu;
  u32 x0 = c0 + ks0, x1 = c1 + ks1;
#define TFR(r) { x0 += x1; x1 = (x1 << r) | (x1 >> (32 - r)); x1 ^= x0; }
  TFR(13) TFR(15) TFR(26) TFR(6)  x0 += ks1; x1 += ks2 + 1u;
  TFR(17) TFR(29) TFR(16) TFR(24) x0 += ks2; x1 += ks0 + 2u;
  TFR(13) TFR(15) TFR(26) TFR(6)  x0 += ks0; x1 += ks1 + 3u;
  TFR(17) TFR(29) TFR(16) TFR(24) x0 += ks1; x1 += ks2 + 4u;
  TFR(13) TFR(15) TFR(26) TFR(6)  x0 += ks2; x1 += ks0 + 5u;
#undef TFR
  uint2 r; r.x = x0; r.y = x1; return r;
}

__device__ __forceinline__ u32 rbits(uint2 key, int i, int n) {
  int h = n >> 1;
  if (i < h) return tf2(key, (u32)i, (u32)(i + h)).x;
  return tf2(key, (u32)(i - h), (u32)i).y;
}

__device__ __forceinline__ float unif(u32 bits, float mn, float mx) {
  float f = __uint_as_float((bits >> 9) | 0x3F800000u) - 1.0f;
  return fmaxf(mn, f * (mx - mn) + mn);
}

__device__ __forceinline__ float gumbelf(u32 bits) {
  float u = unif(bits, 1.17549435e-38f, 1.0f);
  return -logf(-logf(u));
}

__device__ __forceinline__ float erfinvf_x(float x) {
  float w = -log1pf(-x * x);
  float p;
  if (w < 5.0f) {
    w -= 2.5f;
    p = 2.81022636e-08f;
    p = fmaf(p, w, 3.43273939e-07f);
    p = fmaf(p, w, -3.5233877e-06f);
    p = fmaf(p, w, -4.39150654e-06f);
    p = fmaf(p, w, 0.00021858087f);
    p = fmaf(p, w, -0.00125372503f);
    p = fmaf(p, w, -0.00417768164f);
    p = fmaf(p, w, 0.246640727f);
    p = fmaf(p, w, 1.50140941f);
  } else {
    w = sqrtf(w) - 3.0f;
    p = -0.000200214257f;
    p = fmaf(p, w, 0.000100950558f);
    p = fmaf(p, w, 0.00134934322f);
    p = fmaf(p, w, -0.00367342844f);
    p = fmaf(p, w, 0.00573950773f);
    p = fmaf(p, w, -0.0076224613f);
    p = fmaf(p, w, 0.00943887047f);
    p = fmaf(p, w, 1.00167406f);
    p = fmaf(p, w, 2.83297682f);
  }
  return p * x;
}

__device__ __forceinline__ float normalf(u32 bits) {
  float u = unif(bits, -0.99999994f, 1.0f);
  return 1.41421356f * erfinvf_x(u);
}

__device__ __forceinline__ float softplusf_(float x) {
  return fmaxf(x, 0.0f) + log1pf(expf(-fabsf(x)));
}

__device__ __forceinline__ float wave_sum(float v) {
#pragma unroll
  for (int m = 1; m < 64; m <<= 1) v += __shfl_xor(v, m, 64);
  return v;
}

__device__ __forceinline__ float b2f(u32 h) { return __uint_as_float(h << 16); }

#define FMA8M(v0, v1, wv, A) do { \
  A[0]=fmaf((v0).x,(wv),A[0]); A[1]=fmaf((v0).y,(wv),A[1]); \
  A[2]=fmaf((v0).z,(wv),A[2]); A[3]=fmaf((v0).w,(wv),A[3]); \
  A[4]=fmaf((v1).x,(wv),A[4]); A[5]=fmaf((v1).y,(wv),A[5]); \
  A[6]=fmaf((v1).z,(wv),A[6]); A[7]=fmaf((v1).w,(wv),A[7]); } while(0)

#define FMA44(a4, b4, A) do { \
  A[0][0]=fmaf((a4).x,(b4).x,A[0][0]); A[0][1]=fmaf((a4).x,(b4).y,A[0][1]); A[0][2]=fmaf((a4).x,(b4).z,A[0][2]); A[0][3]=fmaf((a4).x,(b4).w,A[0][3]); \
  A[1][0]=fmaf((a4).y,(b4).x,A[1][0]); A[1][1]=fmaf((a4).y,(b4).y,A[1][1]); A[1][2]=fmaf((a4).y,(b4).z,A[1][2]); A[1][3]=fmaf((a4).y,(b4).w,A[1][3]); \
  A[2][0]=fmaf((a4).z,(b4).x,A[2][0]); A[2][1]=fmaf((a4).z,(b4).y,A[2][1]); A[2][2]=fmaf((a4).z,(b4).z,A[2][2]); A[2][3]=fmaf((a4).z,(b4).w,A[2][3]); \
  A[3][0]=fmaf((a4).w,(b4).x,A[3][0]); A[3][1]=fmaf((a4).w,(b4).y,A[3][1]); A[3][2]=fmaf((a4).w,(b4).z,A[3][2]); A[3][3]=fmaf((a4).w,(b4).w,A[3][3]); } while(0)

// ---------------- sentinel (workspace too small diagnostic) ----------------
__global__ void k_sentinel(float* __restrict__ out) {
  if (threadIdx.x < 3) out[threadIdx.x] = 1.2345e8f;
}

// ---------------- init kernels ----------------
__global__ void k_init1(const float* __restrict__ Wdpr, const float* __restrict__ bdpr,
                        float* __restrict__ LOGT, uint2* __restrict__ KEYS,
                        uint2* __restrict__ K1s, uint2* __restrict__ K2s) {
  int tid = threadIdx.x;
  if (tid == 0) {
    uint2 key; key.x = 0u; key.y = 1u;   // jax.random.key(1)
    for (int t = 0; t < TT; t++) {
      KEYS[t] = key;
      uint2 e0 = tf2(key, 0u, 3u);
      uint2 e1 = tf2(key, 1u, 4u);
      key.x = e0.x; key.y = e1.x;        // split(key,3)[0]
    }
  }
  __syncthreads();
  for (int t = tid; t < TT; t += 256) {
    uint2 key = KEYS[t];
    uint2 e0 = tf2(key, 0u, 3u);
    uint2 e1 = tf2(key, 1u, 4u);
    uint2 e2 = tf2(key, 2u, 5u);
    uint2 k1; k1.x = e2.x; k1.y = e0.y;  // split[1]
    uint2 k2; k2.x = e1.y; k2.y = e2.y;  // split[2]
    K1s[t] = k1; K2s[t] = k2;
  }
  if (tid < 64) {
    int i = tid >> 3, j = tid & 7;
    float s = bdpr[j];
#pragma unroll
    for (int k = 0; k < 8; k++) s += ((k == i) ? 0.65f : 0.05f) * Wdpr[j * 8 + k];
    float mx = s;
    for (int m = 1; m < 8; m <<= 1) mx = fmaxf(mx, __shfl_xor(mx, m, 64));
    float e = expf(s - mx);
    float sm = e;
    for (int m = 1; m < 8; m <<= 1) sm += __shfl_xor(sm, m, 64);
    float tr = (e / sm) * 0.5f + ((i == j) ? 0.5f : 0.0f);
    LOGT[i * 8 + j] = logf(tr);
  }
}

__global__ void k_init2(int* __restrict__ EIDX, float* __restrict__ DP, float* __restrict__ ZT) {
  int blk = blockIdx.x, tid = threadIdx.x;
  if (blk == 0) {
    if (tid < BB) {
      uint2 k7; k7.x = 0u; k7.y = 7u;    // jax.random.key(7)
      float best = -1e30f; int bi = 0;
      for (int i = 0; i < DD; i++) {
        float g = gumbelf(rbits(k7, tid * DD + i, BB * DD));
        if (g > best) { best = g; bi = i; }
      }
      EIDX[tid] = bi;
      for (int i = 0; i < DD; i++) DP[tid * DD + i] = 0.125f;
    }
  } else {
    int base = (blk - 1) * 1024 + tid;
    ZT[base] = 0.f; ZT[base + 256] = 0.f; ZT[base + 512] = 0.f; ZT[base + 768] = 0.f;
  }
}

// ---------------- generic two-segment grouped GEMM (f32 VALU) ----------------
// C[g][m][n] = act( sum_k [A0|A1][ga][m][k] * W[gw][n][wofs+k] + bias[gw][n] )
template <int ACT, int OUTBF, int A0BF>
__global__ __launch_bounds__(256)
void gemm2seg(const void* __restrict__ A0v, long a0_gs, int lda0, int K0,
              const float* __restrict__ A1, long a1_gs, int lda1, int K1,
              const float* __restrict__ W, long w_gs, int ldw, int wofs,
              const float* __restrict__ bias, long b_gs,
              void* __restrict__ Cv, long c_gs, int ldc, int gdiv) {
  const int g = blockIdx.z;
  const int ga = g / gdiv, gw = g % DD;
  const float* pW = W + (long)gw * w_gs + wofs;
  const int m0 = blockIdx.x * 64, n0 = blockIdx.y * 64;
  const int tid = threadIdx.x;
  const int tm = tid >> 4, tn = tid & 15;
  __shared__ float As[32][68];
  __shared__ float Bs[32][68];
  float acc[4][4];
#pragma unroll
  for (int r = 0; r < 4; r++)
#pragma unroll
    for (int c = 0; c < 4; c++) acc[r][c] = 0.f;
  const int K = K0 + K1;
  for (int kb = 0; kb < K; kb += 32) {
#pragma unroll
    for (int l = 0; l < 2; l++) {
      int idx = tid + l * 256; int row = idx >> 3, c4 = (idx & 7) << 2;
      float4 v;
      if (kb < K0) {
        if (A0BF) {
          const __hip_bfloat16* p = (const __hip_bfloat16*)A0v + (long)ga * a0_gs + (long)(m0 + row) * lda0 + kb + c4;
          uint2 u = *(const uint2*)p;
          v.x = b2f(u.x & 0xffffu); v.y = b2f(u.x >> 16);
          v.z = b2f(u.y & 0xffffu); v.w = b2f(u.y >> 16);
        } else {
          v = *(const float4*)((const float*)A0v + (long)ga * a0_gs + (long)(m0 + row) * lda0 + kb + c4);
        }
      } else {
        v = *(const float4*)(A1 + (long)ga * a1_gs + (long)(m0 + row) * lda1 + (kb - K0) + c4);
      }
      As[c4 + 0][row] = v.x; As[c4 + 1][row] = v.y; As[c4 + 2][row] = v.z; As[c4 + 3][row] = v.w;
    }
#pragma unroll
    for (int l = 0; l < 2; l++) {
      int idx = tid + l * 256; int row = idx >> 3, c4 = (idx & 7) << 2;
      float4 v = *(const float4*)(pW + (long)(n0 + row) * ldw + kb + c4);
      Bs[c4 + 0][row] = v.x; Bs[c4 + 1][row] = v.y; Bs[c4 + 2][row] = v.z; Bs[c4 + 3][row] = v.w;
    }
    __syncthreads();
#pragma unroll
    for (int k = 0; k < 32; k++) {
      float4 a = *(const float4*)&As[k][tm << 2];
      float4 b = *(const float4*)&Bs[k][tn << 2];
      FMA44(a, b, acc);
    }
    __syncthreads();
  }
#pragma unroll
  for (int r = 0; r < 4; r++) {
    int m = m0 + (tm << 2) + r;
#pragma unroll
    for (int c = 0; c < 4; c++) {
      int n = n0 + (tn << 2) + c;
      float v = acc[r][c];
      if (bias) v += bias[(long)gw * b_gs + n];
      if (ACT == 1) v = fmaxf(v, 0.f);
      if (OUTBF) ((__hip_bfloat16*)Cv)[(long)g * c_gs + (long)m * ldc + n] = __float2bfloat16(v);
      else       ((float*)Cv)[(long)g * c_gs + (long)m * ldc + n] = v;
    }
  }
}

// ---------------- GRU step ----------------
__global__ __launch_bounds__(256)
void k_gru(const float* __restrict__ GI, const float* __restrict__ hprev,
           const float* __restrict__ Whh, const float* __restrict__ bhh,
           float* __restrict__ hout, __hip_bfloat16* __restrict__ houtB) {
  const int bt = blockIdx.x >> 5, jt = blockIdx.x & 31;
  const int b0 = bt * 16, j0 = jt * 16;
  const int tid = threadIdx.x;
  const int bi = tid >> 4, ji = tid & 15;
  __shared__ float ws[48][132];
  __shared__ float hs[16][132];
  float ar = 0.f, az = 0.f, an = 0.f;
  for (int kc = 0; kc < HH; kc += 128) {
    for (int idx = tid; idx < 48 * 32; idx += 256) {
      int r = idx >> 5, c4 = (idx & 31) << 2;
      int jr = r / 3, gr = r % 3;
      int grow = gr * HH + j0 + jr;
      *(float4*)&ws[r][c4] = *(const float4*)(Whh + (long)grow * HH + kc + c4);
    }
    for (int idx = tid; idx < 16 * 32; idx += 256) {
      int r = idx >> 5, c4 = (idx & 31) << 2;
      float4 v;
      if (hprev) v = *(const float4*)(hprev + (long)(b0 + r) * HH + kc + c4);
      else { v.x = v.y = v.z = v.w = 0.f; }
      *(float4*)&hs[r][c4] = v;
    }
    __syncthreads();
    const int r0 = ji * 3;
    for (int k4 = 0; k4 < 128; k4 += 4) {
      float4 hv = *(const float4*)&hs[bi][k4];
      float4 w0 = *(const float4*)&ws[r0 + 0][k4];
      float4 w1 = *(const float4*)&ws[r0 + 1][k4];
      float4 w2 = *(const float4*)&ws[r0 + 2][k4];
      ar = fmaf(hv.x, w0.x, fmaf(hv.y, w0.y, fmaf(hv.z, w0.z, fmaf(hv.w, w0.w, ar))));
      az = fmaf(hv.x, w1.x, fmaf(hv.y, w1.y, fmaf(hv.z, w1.z, fmaf(hv.w, w1.w, az))));
      an = fmaf(hv.x, w2.x, fmaf(hv.y, w2.y, fmaf(hv.z, w2.z, fmaf(hv.w, w2.w, an))));
    }
    __syncthreads();
  }
  int j = j0 + ji, b = b0 + bi;
  float gr_ = ar + bhh[j], gz = az + bhh[HH + j], gn = an + bhh[2 * HH + j];
  const float* gi = GI + (long)b * G3;
  float ir = gi[j], iz = gi[HH + j], inn = gi[2 * HH + j];
  float r = 1.f / (1.f + expf(-(ir + gr_)));
  float zg = 1.f / (1.f + expf(-(iz + gz)));
  float n = tanhf(inn + r * gn);
  float hp = hprev ? hprev[(long)b * HH + j] : 0.f;
  float hnew = (1.f - zg) * n + zg * hp;
  hout[(long)b * HH + j] = hnew;
  if (houtB) houtB[(long)b * HH + j] = __float2bfloat16(hnew);
}

// ---------------- d-posterior (all experts) + kldc_e, chunked (f32 h input) ----------------
__global__ __launch_bounds__(256)
void k_dpa(const float* __restrict__ Wdp, const float* __restrict__ bdp,
           const float* __restrict__ HF, const float* __restrict__ LOGT,
           float* __restrict__ DPA, float* __restrict__ KCE, int t0) {
  const int tl = blockIdx.x; const int t = t0 + tl;
  const int bq = blockIdx.y; const int bb0 = bq * 32;
  const int tid = threadIdx.x;
  const int wv = tid >> 6;
  const int di = tid & 63; const int dd = di >> 3, ii = di & 7;
  __shared__ float obs[32][132];
  float acc[8];
#pragma unroll
  for (int r = 0; r < 8; r++) acc[r] = 0.f;
  for (int kc = 0; kc < HH; kc += 128) {
    for (int idx = tid; idx < 32 * 32; idx += 256) {
      int r = idx >> 5, c4 = (idx & 31) << 2;
      *(float4*)&obs[r][c4] = *(const float4*)(HF + ((long)tl * BB + bb0 + r) * HH + kc + c4);
    }
    __syncthreads();
    const float* wr = Wdp + (long)di * HH + kc;
    for (int k = 0; k < 128; k += 4) {
      float4 w4 = *(const float4*)(wr + k);
#pragma unroll
      for (int r = 0; r < 8; r++) {
        int bl = r * 4 + wv;
        float4 o4 = *(const float4*)&obs[bl][k];
        acc[r] = fmaf(o4.x, w4.x, fmaf(o4.y, w4.y, fmaf(o4.z, w4.z, fmaf(o4.w, w4.w, acc[r]))));
      }
    }
    __syncthreads();
  }
  float bsum = bdp[di];
#pragma unroll
  for (int r = 0; r < 8; r++) {
    int bl = r * 4 + wv; int b = bb0 + bl;
    float v = acc[r] + bsum;
    float mx = v;
    for (int m = 1; m < 8; m <<= 1) mx = fmaxf(mx, __shfl_xor(mx, m, 64));
    float e = expf(v - mx);
    float sm = e;
    for (int m = 1; m < 8; m <<= 1) sm += __shfl_xor(sm, m, 64);
    float p = e / sm;
    DPA[(((long)t * BB + b) * DD + dd) * DD + ii] = p;
    float term = p * (logf(p + 1e-8f) - LOGT[dd * 8 + ii]);
    for (int m = 1; m < 8; m <<= 1) term += __shfl_xor(term, m, 64);
    if (ii == 0) KCE[((long)t * DD + dd) * BB + b] = term;
  }
}

// ---------------- sequential d-trajectory (tiny) ----------------
__global__ void k_dchain(const float* __restrict__ DPA, const uint2* __restrict__ K1s,
                         int* __restrict__ EIDX, float* __restrict__ DP) {
  int b = threadIdx.x;
  if (b >= BB) return;
  int e = EIDX[b];
  for (int t = 0; t < TT; t++) {
    uint2 k1 = K1s[t];
    const float* p = DPA + (((long)t * BB + b) * DD + e) * DD;
    float best = -1e30f; int bi = 0;
#pragma unroll
    for (int i = 0; i < DD; i++) {
      float pi = p[i];
      DP[((long)(t + 1) * BB + b) * DD + i] = pi;
      float sc = logf(pi) + gumbelf(rbits(k1, b * DD + i, BB * DD));
      if (sc > best) { best = sc; bi = i; }
    }
    e = bi;
    EIDX[(t + 1) * BB + b] = e;
  }
}

// ---------------- fused sequential scan step ----------------
// 128 blocks: d = blk&7, b-tile of 8. d-trajectory precomputed (EIDX).
__global__ __launch_bounds__(256)
void k_step(int t, const int* __restrict__ EIDX, const uint2* __restrict__ K2s,
            const __hip_bfloat16* __restrict__ OBPc,
            const float* __restrict__ Wq1, const float* __restrict__ bq1,
            const float* __restrict__ Wq2, const float* __restrict__ bq2,
            const float* __restrict__ Wqm, const float* __restrict__ bqm,
            const float* __restrict__ Wqs, const float* __restrict__ bqs,
            float* __restrict__ ZT) {
  const int d = blockIdx.x & 7, bt = blockIdx.x >> 3;
  const int b0 = bt * 8;
  const int tid = threadIdx.x;
  __shared__ float zt_s[256][8];
  __shared__ float h1t[256][8];
  __shared__ float h2t[256][8];
  __shared__ int en_s[8];
  for (int i = tid; i < 8 * 256; i += 256) {
    int bl = i >> 8, k = i & 255;
    zt_s[k][bl] = ZT[((long)t * BB + b0 + bl) * ZZ + k];
  }
  if (tid < 8) en_s[tid] = EIDX[(t + 1) * BB + b0 + tid];
  __syncthreads();
  // phase 1: h1 = relu(OBPc + Wq1z @ z_prev + bq1)
  {
    const int j = tid;
    const float* wr = Wq1 + ((long)(d * ZZ + j)) * 768 + 512;
    const __hip_bfloat16* obr = OBPc + (((long)d * TC + (t & (TC - 1))) * BB + b0) * ZZ + j;
    float bj = bq1[d * ZZ + j];
    float acc[8];
#pragma unroll
    for (int bl = 0; bl < 8; bl++) acc[bl] = bj + __bfloat162float(obr[bl * ZZ]);
    for (int k = 0; k < ZZ; k += 4) {
      float4 w4 = *(const float4*)(wr + k);
      float4 z0, z1;
      z0 = *(const float4*)&zt_s[k + 0][0]; z1 = *(const float4*)&zt_s[k + 0][4]; FMA8M(z0, z1, w4.x, acc);
      z0 = *(const float4*)&zt_s[k + 1][0]; z1 = *(const float4*)&zt_s[k + 1][4]; FMA8M(z0, z1, w4.y, acc);
      z0 = *(const float4*)&zt_s[k + 2][0]; z1 = *(const float4*)&zt_s[k + 2][4]; FMA8M(z0, z1, w4.z, acc);
      z0 = *(const float4*)&zt_s[k + 3][0]; z1 = *(const float4*)&zt_s[k + 3][4]; FMA8M(z0, z1, w4.w, acc);
    }
#pragma unroll
    for (int bl = 0; bl < 8; bl++) h1t[j][bl] = fmaxf(acc[bl], 0.f);
  }
  __syncthreads();
  // phase 2: h2 = relu(Wq2 @ h1 + bq2)
  {
    const int j = tid;
    const float* wr = Wq2 + ((long)(d * ZZ + j)) * ZZ;
    float bj = bq2[d * ZZ + j];
    float acc[8];
#pragma unroll
    for (int bl = 0; bl < 8; bl++) acc[bl] = bj;
    for (int k = 0; k < ZZ; k += 4) {
      float4 w4 = *(const float4*)(wr + k);
      float4 z0, z1;
      z0 = *(const float4*)&h1t[k + 0][0]; z1 = *(const float4*)&h1t[k + 0][4]; FMA8M(z0, z1, w4.x, acc);
      z0 = *(const float4*)&h1t[k + 1][0]; z1 = *(const float4*)&h1t[k + 1][4]; FMA8M(z0, z1, w4.y, acc);
      z0 = *(const float4*)&h1t[k + 2][0]; z1 = *(const float4*)&h1t[k + 2][4]; FMA8M(z0, z1, w4.z, acc);
      z0 = *(const float4*)&h1t[k + 3][0]; z1 = *(const float4*)&h1t[k + 3][4]; FMA8M(z0, z1, w4.w, acc);
    }
#pragma unroll
    for (int bl = 0; bl < 8; bl++) h2t[j][bl] = fmaxf(acc[bl], 0.f);
  }
  __syncthreads();
  // phase 3: heads qm / qs(raw)
  float qm[8], qs[8];
  {
    const int j = tid;
    const float* wm = Wqm + ((long)(d * ZZ + j)) * ZZ;
    const float* wsd = Wqs + ((long)(d * ZZ + j)) * ZZ;
    float bm_ = bqm[d * ZZ + j], bs__ = bqs[d * ZZ + j];
#pragma unroll
    for (int bl = 0; bl < 8; bl++) { qm[bl] = bm_; qs[bl] = bs__; }
    for (int k = 0; k < ZZ; k += 4) {
      float4 wm4 = *(const float4*)(wm + k);
      float4 ws4 = *(const float4*)(wsd + k);
#pragma unroll
      for (int kk = 0; kk < 4; kk++) {
        float wmv = kk == 0 ? wm4.x : kk == 1 ? wm4.y : kk == 2 ? wm4.z : wm4.w;
        float wsv = kk == 0 ? ws4.x : kk == 1 ? ws4.y : kk == 2 ? ws4.z : ws4.w;
        float4 h0 = *(const float4*)&h2t[k + kk][0];
        float4 h1v = *(const float4*)&h2t[k + kk][4];
        FMA8M(h0, h1v, wmv, qm);
        FMA8M(h0, h1v, wsv, qs);
      }
    }
  }
  // phase 4: z sample (only block with matching expert writes)
#pragma unroll
  for (int bl = 0; bl < 8; bl++) {
    if (en_s[bl] == d) {
      int b = b0 + bl;
      float eps = normalf(rbits(K2s[t], b * ZZ + tid, BB * ZZ));
      ZT[((long)(t + 1) * BB + b) * ZZ + tid] = qm[bl] + softplusf_(qs[bl]) * eps;
    }
  }
}

// ---------------- loss-pass heads + reductions ----------------
__global__ __launch_bounds__(256)
void k_heads_pq(const float* __restrict__ LA, const float* __restrict__ LB,
                const float* __restrict__ Wpm, const float* __restrict__ bpm,
                const float* __restrict__ Wps, const float* __restrict__ bps,
                const float* __restrict__ Wqm, const float* __restrict__ bqm,
                const float* __restrict__ Wqs, const float* __restrict__ bqs,
                const float* __restrict__ DP, float* __restrict__ PART, int t0) {
  const int g = blockIdx.z; const int tl = g >> 3, d = g & 7; const int t = t0 + tl;
  const int m0 = blockIdx.x * 64, n0 = blockIdx.y * 64;
  const int tid = threadIdx.x; const int tm = tid >> 4, tn = tid & 15;
  __shared__ float As[32][68], W1s[32][68], W2s[32][68];
  float aPm[4][4], aPs[4][4], aQm[4][4], aQs[4][4];
#pragma unroll
  for (int r = 0; r < 4; r++)
#pragma unroll
    for (int c = 0; c < 4; c++) { aPm[r][c] = 0.f; aPs[r][c] = 0.f; aQm[r][c] = 0.f; aQs[r][c] = 0.f; }

#define HEADPASS(Abase, Wm_, Ws_, ACCM, ACCS) \
  { const float* Ap = (Abase) + (long)g * (BB * ZZ); \
    const float* Wm = (Wm_) + (long)d * ZZ * ZZ; \
    const float* Wsp = (Ws_) + (long)d * ZZ * ZZ; \
    for (int kb = 0; kb < ZZ; kb += 32) { \
      for (int l = 0; l < 2; l++) { \
        int idx = tid + l * 256; int row = idx >> 3, c4 = (idx & 7) << 2; \
        float4 v = *(const float4*)(Ap + (long)(m0 + row) * ZZ + kb + c4); \
        As[c4+0][row]=v.x; As[c4+1][row]=v.y; As[c4+2][row]=v.z; As[c4+3][row]=v.w; \
        v = *(const float4*)(Wm + (long)(n0 + row) * ZZ + kb + c4); \
        W1s[c4+0][row]=v.x; W1s[c4+1][row]=v.y; W1s[c4+2][row]=v.z; W1s[c4+3][row]=v.w; \
        v = *(const float4*)(Wsp + (long)(n0 + row) * ZZ + kb + c4); \
        W2s[c4+0][row]=v.x; W2s[c4+1][row]=v.y; W2s[c4+2][row]=v.z; W2s[c4+3][row]=v.w; \
      } \
      __syncthreads(); \
      _Pragma("unroll") \
      for (int k = 0; k < 32; k++) { \
        float4 a = *(const float4*)&As[k][tm << 2]; \
        float4 b1 = *(const float4*)&W1s[k][tn << 2]; \
        float4 b2 = *(const float4*)&W2s[k][tn << 2]; \
        FMA44(a, b1, ACCM); \
        FMA44(a, b2, ACCS); \
      } \
      __syncthreads(); \
    } }

  HEADPASS(LA, Wpm, Wps, aPm, aPs)
  HEADPASS(LB, Wqm, Wqs, aQm, aQs)

  float local = 0.f;
#pragma unroll
  for (int r = 0; r < 4; r++) {
    int b = m0 + (tm << 2) + r;
    float w8 = DP[((long)(t + 1) * BB + b) * DD + d];
#pragma unroll
    for (int c = 0; c < 4; c++) {
      int n = n0 + (tn << 2) + c;
      float pm = aPm[r][c] + bpm[d * ZZ + n];
      float ps = softplusf_(aPs[r][c] + bps[d * ZZ + n]);
      float qm = aQm[r][c] + bqm[d * ZZ + n];
      float qs = softplusf_(aQs[r][c] + bqs[d * ZZ + n]);
      float dm = qm - pm;
      local += 0.5f * w8 * (2.f * logf(ps / qs) + (qs * qs + dm * dm) / (ps * ps) - 1.f);
    }
  }
  local = wave_sum(local);
  __shared__ float red[4];
  int wid = tid >> 6;
  if ((tid & 63) == 0) red[wid] = local;
  __syncthreads();
  if (tid == 0) atomicAdd(&PART[((long)t * DD + d) * 4 + 0], red[0] + red[1] + red[2] + red[3]);
}

__global__ __launch_bounds__(256)
void k_heads_e(const float* __restrict__ LA,
               const float* __restrict__ Wem, const float* __restrict__ bem,
               const float* __restrict__ Wes, const float* __restrict__ bes,
               const float* __restrict__ yy, const float* __restrict__ DP,
               const float* __restrict__ KCE, float* __restrict__ PART, int t0) {
  const int g = blockIdx.z; const int tl = g >> 3, d = g & 7; const int t = t0 + tl;
  const int m0 = blockIdx.x * 64, n0 = blockIdx.y * 64;
  const int tid = threadIdx.x; const int tm = tid >> 4, tn = tid & 15;
  __shared__ float As[32][68], W1s[32][68], W2s[32][68];
  float aM[4][4], aS[4][4];
#pragma unroll
  for (int r = 0; r < 4; r++)
#pragma unroll
    for (int c = 0; c < 4; c++) { aM[r][c] = 0.f; aS[r][c] = 0.f; }
  {
    const float* Ap = LA + (long)g * (BB * ZZ);
    const float* Wm = Wem + (long)d * YY * YY;
    const float* Wsp = Wes + (long)d * YY * YY;
    for (int kb = 0; kb < YY; kb += 32) {
      for (int l = 0; l < 2; l++) {
        int idx = tid + l * 256; int row = idx >> 3, c4 = (idx & 7) << 2;
        float4 v = *(const float4*)(Ap + (long)(m0 + row) * YY + kb + c4);
        As[c4+0][row]=v.x; As[c4+1][row]=v.y; As[c4+2][row]=v.z; As[c4+3][row]=v.w;
        v = *(const float4*)(Wm + (long)(n0 + row) * YY + kb + c4);
        W1s[c4+0][row]=v.x; W1s[c4+1][row]=v.y; W1s[c4+2][row]=v.z; W1s[c4+3][row]=v.w;
        v = *(const float4*)(Wsp + (long)(n0 + row) * YY + kb + c4);
        W2s[c4+0][row]=v.x; W2s[c4+1][row]=v.y; W2s[c4+2][row]=v.z; W2s[c4+3][row]=v.w;
      }
      __syncthreads();
#pragma unroll
      for (int k = 0; k < 32; k++) {
        float4 a = *(const float4*)&As[k][tm << 2];
        float4 b1 = *(const float4*)&W1s[k][tn << 2];
        float4 b2 = *(const float4*)&W2s[k][tn << 2];
        FMA44(a, b1, aM);
        FMA44(a, b2, aS);
      }
      __syncthreads();
    }
  }
  float local = 0.f;
#pragma unroll
  for (int r = 0; r < 4; r++) {
    int b = m0 + (tm << 2) + r;
    float w8 = DP[((long)(t + 1) * BB + b) * DD + d];
#pragma unroll
    for (int c = 0; c < 4; c++) {
      int n = n0 + (tn << 2) + c;
      float ym = aM[r][c] + bem[d * YY + n];
      float ys = softplusf_(aS[r][c] + bes[d * YY + n]);
      float yv = yy[((long)t * BB + b) * YY + n];
      float rr = (yv - ym) / ys;
      local += w8 * 0.5f * (1.8378770664093453f + 2.f * logf(ys) + rr * rr);
    }
  }
  local = wave_sum(local);
  __shared__ float red[4];
  int wid = tid >> 6;
  if ((tid & 63) == 0) red[wid] = local;
  __syncthreads();
  if (tid == 0) atomicAdd(&PART[((long)t * DD + d) * 4 + 2], red[0] + red[1] + red[2] + red[3]);
  if (blockIdx.x == 0 && blockIdx.y == 0) {
    __syncthreads();
    float v = 0.f;
    if (tid < BB) v = KCE[((long)t * DD + d) * BB + tid] * DP[((long)t * BB + tid) * DD + d];
    v = wave_sum(v);
    if ((tid & 63) == 0) red[wid] = v;
    __syncthreads();
    if (tid == 0) atomicAdd(&PART[((long)t * DD + d) * 4 + 1], red[0] + red[1] + red[2] + red[3]);
  }
}

__global__ void k_fin(const float* __restrict__ PART, float* __restrict__ out) {
  int tid = threadIdx.x;
  float s0 = 0.f, s1 = 0.f, s2 = 0.f;
  for (int i = tid; i < TT * DD; i += 256) {
    s0 += PART[i * 4 + 0]; s1 += PART[i * 4 + 1]; s2 += PART[i * 4 + 2];
  }
  s0 = wave_sum(s0); s1 = wave_sum(s1); s2 = wave_sum(s2);
  __shared__ float r0[4], r1[4], r2[4];
  int wid = tid >> 6;
  if ((tid & 63) == 0) { r0[wid] = s0; r1[wid] = s1; r2[wid] = s2; }
  __syncthreads();
  if (tid == 0) {
    out[0] = r0[0] + r0[1] + r0[2] + r0[3];
    out[1] = r1[0] + r1[1] + r1[2] + r1[3];
    out[2] = r2[0] + r2[1] + r2[2] + r2[3];
  }
}

// ---------------- host launcher ----------------
extern "C" void kernel_launch(void* const* d_in, const int* in_sizes, int n_in,
                              void* d_out, int out_size, void* d_ws, size_t ws_size,
                              hipStream_t stream) {
  (void)in_sizes; (void)n_in; (void)out_size;
  const float* x      = (const float*)d_in[0];
  const float* y      = (const float*)d_in[1];
  const float* Wdpr   = (const float*)d_in[2];
  const float* bdpr   = (const float*)d_in[3];
  const float* Wdp    = (const float*)d_in[4];
  const float* bdp    = (const float*)d_in[5];
  const float* Wq1    = (const float*)d_in[6];
  const float* bq1    = (const float*)d_in[7];
  const float* Wq2    = (const float*)d_in[8];
  const float* bq2    = (const float*)d_in[9];
  const float* Wqm    = (const float*)d_in[10];
  const float* bqm    = (const float*)d_in[11];
  const float* Wqs    = (const float*)d_in[12];
  const float* bqs    = (const float*)d_in[13];
  const float* Wp1    = (const float*)d_in[14];
  const float* bp1    = (const float*)d_in[15];
  const float* Wp2    = (const float*)d_in[16];
  const float* bp2    = (const float*)d_in[17];
  const float* Wpm    = (const float*)d_in[18];
  const float* bpm    = (const float*)d_in[19];
  const float* Wps    = (const float*)d_in[20];
  const float* bps    = (const float*)d_in[21];
  const float* We1    = (const float*)d_in[22];
  const float* be1    = (const float*)d_in[23];
  const float* We2    = (const float*)d_in[24];
  const float* be2    = (const float*)d_in[25];
  const float* Wem    = (const float*)d_in[26];
  const float* bem    = (const float*)d_in[27];
  const float* Wes    = (const float*)d_in[28];
  const float* bes    = (const float*)d_in[29];
  const float* Wih_f  = (const float*)d_in[30];
  const float* Whh_f  = (const float*)d_in[31];
  const float* bih_f  = (const float*)d_in[32];
  const float* bhh_f  = (const float*)d_in[33];
  const float* Wih_b  = (const float*)d_in[34];
  const float* Whh_b  = (const float*)d_in[35];
  const float* bih_b  = (const float*)d_in[36];
  const float* bhh_b  = (const float*)d_in[37];

  char* base = (char*)d_ws;
  size_t off = 0;
  auto alloc = [&](size_t bytes) -> char* {
    char* p = base + off;
    off += (bytes + 1023) & ~(size_t)1023;
    return p;
  };
  float* LOGT = (float*)alloc(64 * 4);
  uint2* KEYS = (uint2*)alloc(TT * 8);
  uint2* K1s  = (uint2*)alloc(TT * 8);
  uint2* K2s  = (uint2*)alloc(TT * 8);
  int*   EIDX = (int*)alloc((size_t)(TT + 1) * BB * 4);
  float* DP   = (float*)alloc((size_t)(TT + 1) * BB * DD * 4);
  float* DPA  = (float*)alloc((size_t)TT * BB * DD * DD * 4);
  float* KCE  = (float*)alloc((size_t)TT * DD * BB * 4);
  float* ZT   = (float*)alloc((size_t)(TT + 1) * BB * ZZ * 4);
  float* PART = (float*)alloc((size_t)TT * DD * 4 * 4);
  float* OF   = (float*)alloc((size_t)TT * BB * HH * 4);          // f32 (d-path fidelity + loss)
  __hip_bfloat16* OB = (__hip_bfloat16*)alloc((size_t)TT * BB * HH * 2);  // bf16 (z-path/loss only)
  float* HROLL = (float*)alloc((size_t)TC * BB * HH * 4);         // f32 rolling backward h
  char*  SH   = alloc((size_t)TC * BB * G3 * 4);                  // 25.2MB shared region
  float* GIc  = (float*)SH;
  __hip_bfloat16* OBPc = (__hip_bfloat16*)SH;
  float* LH1  = (float*)SH;
  float* LH2A = LH1 + (size_t)CH * DD * BB * ZZ;
  float* LH2B = LH2A + (size_t)CH * DD * BB * ZZ;

  if (ws_size < off) {   // workspace too small: emit sentinel instead of faulting
    k_sentinel<<<1, 64, 0, stream>>>((float*)d_out);
    return;
  }

  hipMemsetAsync(PART, 0, (size_t)TT * DD * 4 * 4, stream);
  k_init1<<<1, 256, 0, stream>>>(Wdpr, bdpr, LOGT, KEYS, K1s, K2s);
  k_init2<<<33, 256, 0, stream>>>(EIDX, DP, ZT);

  const long BH = (long)BB * HH, BZ = (long)BB * ZZ, BG = (long)BB * G3;

  // forward GRU, chunked input projection
  for (int c = 0; c < TT / TC; c++) {
    int t0 = c * TC;
    gemm2seg<0, 0, 0><<<dim3(64, 24, 1), 256, 0, stream>>>(
        x + (long)t0 * BB * XX, 0, XX, XX, nullptr, 0, 4, 0,
        Wih_f, 0, XX, 0, bih_f, 0, GIc, 0, G3, 1);
    for (int tl = 0; tl < TC; tl++) {
      int t = t0 + tl;
      k_gru<<<256, 256, 0, stream>>>(GIc + (long)tl * BG,
                                     t ? (OF + (long)(t - 1) * BH) : nullptr,
                                     Whh_f, bhh_f, OF + (long)t * BH, nullptr);
    }
  }
  // backward GRU (reversed time), chunked; f32 h in HROLL, bf16 persist in OB
  for (int c = TT / TC - 1; c >= 0; c--) {
    int t0 = c * TC;
    gemm2seg<0, 0, 0><<<dim3(64, 24, 1), 256, 0, stream>>>(
        y + (long)t0 * BB * YY, 0, YY, YY, OF + (long)t0 * BH, 0, HH, HH,
        Wih_b, 0, 768, 0, bih_b, 0, GIc, 0, G3, 1);
    for (int tl = TC - 1; tl >= 0; tl--) {
      int t = t0 + tl;
      k_gru<<<256, 256, 0, stream>>>(GIc + (long)tl * BG,
                                     (t == TT - 1) ? nullptr : (HROLL + (long)((t + 1) & (TC - 1)) * BH),
                                     Whh_b, bhh_b, HROLL + (long)(t & (TC - 1)) * BH, OB + (long)t * BH);
    }
    k_dpa<<<dim3(TC, 4), 256, 0, stream>>>(Wdp, bdp, HROLL, LOGT, DPA, KCE, t0);
  }
  // sequential d-trajectory
  k_dchain<<<1, 128, 0, stream>>>(DPA, K1s, EIDX, DP);
  // z-scan, chunked OBP hoist
  for (int c = 0; c < TT / TC; c++) {
    int t0 = c * TC;
    gemm2seg<0, 1, 1><<<dim3(64, 4, 8), 256, 0, stream>>>(
        OB + (long)t0 * BH, 0, HH, HH, nullptr, 0, 4, 0,
        Wq1, (long)ZZ * 768, 768, 0, nullptr, 0, OBPc, (long)TC * BB * ZZ, ZZ, 8);
    for (int tl = 0; tl < TC; tl++) {
      k_step<<<128, 256, 0, stream>>>(t0 + tl, EIDX, K2s, OBPc,
                                      Wq1, bq1, Wq2, bq2, Wqm, bqm, Wqs, bqs, ZT);
    }
  }
  // parallel loss pass, chunked over t
  for (int c = 0; c < TT / CH; c++) {
    int t0 = c * CH;
    dim3 gl(2, 4, CH * DD);
    // p branch
    gemm2seg<1, 0, 0><<<gl, 256, 0, stream>>>(
        OF + (long)t0 * BH, BH, HH, HH, ZT + (long)t0 * BZ, BZ, ZZ, ZZ,
        Wp1, (long)ZZ * 768, 768, 0, bp1, ZZ, LH1, BZ, ZZ, 8);
    gemm2seg<1, 0, 0><<<gl, 256, 0, stream>>>(
        LH1, BZ, ZZ, ZZ, nullptr, 0, 4, 0,
        Wp2, (long)ZZ * ZZ, ZZ, 0, bp2, ZZ, LH2A, BZ, ZZ, 1);
    // q branch (A0 = OB bf16, K=768)
    gemm2seg<1, 0, 1><<<gl, 256, 0, stream>>>(
        OB + (long)t0 * BH, BH, HH, HH, ZT + (long)t0 * BZ, BZ, ZZ, ZZ,
        Wq1, (long)ZZ * 768, 768, 0, bq1, ZZ, LH1, BZ, ZZ, 8);
    gemm2seg<1, 0, 0><<<gl, 256, 0, stream>>>(
        LH1, BZ, ZZ, ZZ, nullptr, 0, 4, 0,
        Wq2, (long)ZZ * ZZ, ZZ, 0, bq2, ZZ, LH2B, BZ, ZZ, 1);
    k_heads_pq<<<gl, 256, 0, stream>>>(LH2A, LH2B, Wpm, bpm, Wps, bps,
                                       Wqm, bqm, Wqs, bqs, DP, PART, t0);
    // e branch
    gemm2seg<1, 0, 0><<<gl, 256, 0, stream>>>(
        OF + (long)t0 * BH, BH, HH, HH, ZT + (long)(t0 + 1) * BZ, BZ, ZZ, ZZ,
        We1, (long)YY * 768, 768, 0, be1, YY, LH1, BZ, ZZ, 8);
    gemm2seg<1, 0, 0><<<gl, 256, 0, stream>>>(
        LH1, BZ, ZZ, ZZ, nullptr, 0, 4, 0,
        We2, (long)YY * YY, YY, 0, be2, YY, LH2A, BZ, ZZ, 1);
    k_heads_e<<<gl, 256, 0, stream>>>(LH2A, Wem, bem, Wes, bes, y, DP, KCE, PART, t0);
  }
  k_fin<<<1, 256, 0, stream>>>(PART, (float*)d_out);
}

// Round 7
// 27055.185 us; speedup vs baseline: 1.1882x; 1.1882x over previous
//
#include <hip/hip_runtime.h>
#include <hip/hip_bf16.h>
#include <math.h>
#include <stdint.h>

#define TT 256
#define BB 128
#define XX 128
#define YY 256
#define HH 512
#define ZZ 256
#define DD 8
#define G3 1536
#define CH 8    // loss-pass t-chunk
#define TC 32   // GRU / scan t-chunk

typedef unsigned int u32;
typedef __attribute__((ext_vector_type(8))) short bf16x8;
typedef __attribute__((ext_vector_type(4))) float f32x4;

// ---------------- JAX threefry2x32 PRNG ----------------
__device__ __forceinline__ uint2 tf2(uint2 key, u32 c0, u32 c1) {
  u32 ks0 = key.x, ks1 = key.y, ks2 = ks0 ^ ks1 ^ 0x1BD11BDAu;
  u32 x0 = c0 + ks0, x1 = c1 + ks1;
#define TFR(r) { x0 += x1; x1 = (x1 << r) | (x1 >> (32 - r)); x1 ^= x0; }
  TFR(13) TFR(15) TFR(26) TFR(6)  x0 += ks1; x1 += ks2 + 1u;
  TFR(17) TFR(29) TFR(16) TFR(24) x0 += ks2; x1 += ks0 + 2u;
  TFR(13) TFR(15) TFR(26) TFR(6)  x0 += ks0; x1 += ks1 + 3u;
  TFR(17) TFR(29) TFR(16) TFR(24) x0 += ks1; x1 += ks2 + 4u;
  TFR(13) TFR(15) TFR(26) TFR(6)  x0 += ks2; x1 += ks0 + 5u;
#undef TFR
  uint2 r; r.x = x0; r.y = x1; return r;
}

__device__ __forceinline__ u32 rbits(uint2 key, int i, int n) {
  int h = n >> 1;
  if (i < h) return tf2(key, (u32)i, (u32)(i + h)).x;
  return tf2(key, (u32)(i - h), (u32)i).y;
}

__device__ __forceinline__ float unif(u32 bits, float mn, float mx) {
  float f = __uint_as_float((bits >> 9) | 0x3F800000u) - 1.0f;
  return fmaxf(mn, f * (mx - mn) + mn);
}

__device__ __forceinline__ float gumbelf(u32 bits) {
  float u = unif(bits, 1.17549435e-38f, 1.0f);
  return -logf(-logf(u));
}

__device__ __forceinline__ float erfinvf_x(float x) {
  float w = -log1pf(-x * x);
  float p;
  if (w < 5.0f) {
    w -= 2.5f;
    p = 2.81022636e-08f;
    p = fmaf(p, w, 3.43273939e-07f);
    p = fmaf(p, w, -3.5233877e-06f);
    p = fmaf(p, w, -4.39150654e-06f);
    p = fmaf(p, w, 0.00021858087f);
    p = fmaf(p, w, -0.00125372503f);
    p = fmaf(p, w, -0.00417768164f);
    p = fmaf(p, w, 0.246640727f);
    p = fmaf(p, w, 1.50140941f);
  } else {
    w = sqrtf(w) - 3.0f;
    p = -0.000200214257f;
    p = fmaf(p, w, 0.000100950558f);
    p = fmaf(p, w, 0.00134934322f);
    p = fmaf(p, w, -0.00367342844f);
    p = fmaf(p, w, 0.00573950773f);
    p = fmaf(p, w, -0.0076224613f);
    p = fmaf(p, w, 0.00943887047f);
    p = fmaf(p, w, 1.00167406f);
    p = fmaf(p, w, 2.83297682f);
  }
  return p * x;
}

__device__ __forceinline__ float normalf(u32 bits) {
  float u = unif(bits, -0.99999994f, 1.0f);
  return 1.41421356f * erfinvf_x(u);
}

__device__ __forceinline__ float softplusf_(float x) {
  return fmaxf(x, 0.0f) + log1pf(expf(-fabsf(x)));
}

__device__ __forceinline__ float wave_sum(float v) {
#pragma unroll
  for (int m = 1; m < 64; m <<= 1) v += __shfl_xor(v, m, 64);
  return v;
}

__device__ __forceinline__ float b2f(u32 h) { return __uint_as_float(h << 16); }

__device__ __forceinline__ short f2b(float f) {
  __hip_bfloat16 h = __float2bfloat16(f);
  return *reinterpret_cast<short*>(&h);
}

#define FMA8M(v0, v1, wv, A) do { \
  A[0]=fmaf((v0).x,(wv),A[0]); A[1]=fmaf((v0).y,(wv),A[1]); \
  A[2]=fmaf((v0).z,(wv),A[2]); A[3]=fmaf((v0).w,(wv),A[3]); \
  A[4]=fmaf((v1).x,(wv),A[4]); A[5]=fmaf((v1).y,(wv),A[5]); \
  A[6]=fmaf((v1).z,(wv),A[6]); A[7]=fmaf((v1).w,(wv),A[7]); } while(0)

#define FMA44(a4, b4, A) do { \
  A[0][0]=fmaf((a4).x,(b4).x,A[0][0]); A[0][1]=fmaf((a4).x,(b4).y,A[0][1]); A[0][2]=fmaf((a4).x,(b4).z,A[0][2]); A[0][3]=fmaf((a4).x,(b4).w,A[0][3]); \
  A[1][0]=fmaf((a4).y,(b4).x,A[1][0]); A[1][1]=fmaf((a4).y,(b4).y,A[1][1]); A[1][2]=fmaf((a4).y,(b4).z,A[1][2]); A[1][3]=fmaf((a4).y,(b4).w,A[1][3]); \
  A[2][0]=fmaf((a4).z,(b4).x,A[2][0]); A[2][1]=fmaf((a4).z,(b4).y,A[2][1]); A[2][2]=fmaf((a4).z,(b4).z,A[2][2]); A[2][3]=fmaf((a4).z,(b4).w,A[2][3]); \
  A[3][0]=fmaf((a4).w,(b4).x,A[3][0]); A[3][1]=fmaf((a4).w,(b4).y,A[3][1]); A[3][2]=fmaf((a4).w,(b4).z,A[3][2]); A[3][3]=fmaf((a4).w,(b4).w,A[3][3]); } while(0)

// ---------------- sentinel (workspace too small diagnostic) ----------------
__global__ void k_sentinel(float* __restrict__ out) {
  if (threadIdx.x < 3) out[threadIdx.x] = 1.2345e8f;
}

// ---------------- init kernels ----------------
__global__ void k_init1(const float* __restrict__ Wdpr, const float* __restrict__ bdpr,
                        float* __restrict__ LOGT, uint2* __restrict__ KEYS,
                        uint2* __restrict__ K1s, uint2* __restrict__ K2s) {
  int tid = threadIdx.x;
  if (tid == 0) {
    uint2 key; key.x = 0u; key.y = 1u;   // jax.random.key(1)
    for (int t = 0; t < TT; t++) {
      KEYS[t] = key;
      uint2 e0 = tf2(key, 0u, 3u);
      uint2 e1 = tf2(key, 1u, 4u);
      key.x = e0.x; key.y = e1.x;        // split(key,3)[0]
    }
  }
  __syncthreads();
  for (int t = tid; t < TT; t += 256) {
    uint2 key = KEYS[t];
    uint2 e0 = tf2(key, 0u, 3u);
    uint2 e1 = tf2(key, 1u, 4u);
    uint2 e2 = tf2(key, 2u, 5u);
    uint2 k1; k1.x = e2.x; k1.y = e0.y;  // split[1]
    uint2 k2; k2.x = e1.y; k2.y = e2.y;  // split[2]
    K1s[t] = k1; K2s[t] = k2;
  }
  if (tid < 64) {
    int i = tid >> 3, j = tid & 7;
    float s = bdpr[j];
#pragma unroll
    for (int k = 0; k < 8; k++) s += ((k == i) ? 0.65f : 0.05f) * Wdpr[j * 8 + k];
    float mx = s;
    for (int m = 1; m < 8; m <<= 1) mx = fmaxf(mx, __shfl_xor(mx, m, 64));
    float e = expf(s - mx);
    float sm = e;
    for (int m = 1; m < 8; m <<= 1) sm += __shfl_xor(sm, m, 64);
    float tr = (e / sm) * 0.5f + ((i == j) ? 0.5f : 0.0f);
    LOGT[i * 8 + j] = logf(tr);
  }
}

__global__ void k_init2(int* __restrict__ EIDX, float* __restrict__ DP, float* __restrict__ ZT) {
  int blk = blockIdx.x, tid = threadIdx.x;
  if (blk == 0) {
    if (tid < BB) {
      uint2 k7; k7.x = 0u; k7.y = 7u;    // jax.random.key(7)
      float best = -1e30f; int bi = 0;
      for (int i = 0; i < DD; i++) {
        float g = gumbelf(rbits(k7, tid * DD + i, BB * DD));
        if (g > best) { best = g; bi = i; }
      }
      EIDX[tid] = bi;
      for (int i = 0; i < DD; i++) DP[tid * DD + i] = 0.125f;
    }
  } else {
    int base = (blk - 1) * 1024 + tid;
    ZT[base] = 0.f; ZT[base + 256] = 0.f; ZT[base + 512] = 0.f; ZT[base + 768] = 0.f;
  }
}

// ---------------- generic two-segment grouped GEMM (f32 VALU) ----------------
// kept for the d-path-critical gi projections (must stay f32 — gumbel-argmax
// trajectory flips if gi is bf16-rounded)
template <int ACT, int OUTBF, int A0BF>
__global__ __launch_bounds__(256)
void gemm2seg(const void* __restrict__ A0v, long a0_gs, int lda0, int K0,
              const float* __restrict__ A1, long a1_gs, int lda1, int K1,
              const float* __restrict__ W, long w_gs, int ldw, int wofs,
              const float* __restrict__ bias, long b_gs,
              void* __restrict__ Cv, long c_gs, int ldc, int gdiv) {
  const int g = blockIdx.z;
  const int ga = g / gdiv, gw = g % DD;
  const float* pW = W + (long)gw * w_gs + wofs;
  const int m0 = blockIdx.x * 64, n0 = blockIdx.y * 64;
  const int tid = threadIdx.x;
  const int tm = tid >> 4, tn = tid & 15;
  __shared__ float As[32][68];
  __shared__ float Bs[32][68];
  float acc[4][4];
#pragma unroll
  for (int r = 0; r < 4; r++)
#pragma unroll
    for (int c = 0; c < 4; c++) acc[r][c] = 0.f;
  const int K = K0 + K1;
  for (int kb = 0; kb < K; kb += 32) {
#pragma unroll
    for (int l = 0; l < 2; l++) {
      int idx = tid + l * 256; int row = idx >> 3, c4 = (idx & 7) << 2;
      float4 v;
      if (kb < K0) {
        if (A0BF) {
          const __hip_bfloat16* p = (const __hip_bfloat16*)A0v + (long)ga * a0_gs + (long)(m0 + row) * lda0 + kb + c4;
          uint2 u = *(const uint2*)p;
          v.x = b2f(u.x & 0xffffu); v.y = b2f(u.x >> 16);
          v.z = b2f(u.y & 0xffffu); v.w = b2f(u.y >> 16);
        } else {
          v = *(const float4*)((const float*)A0v + (long)ga * a0_gs + (long)(m0 + row) * lda0 + kb + c4);
        }
      } else {
        v = *(const float4*)(A1 + (long)ga * a1_gs + (long)(m0 + row) * lda1 + (kb - K0) + c4);
      }
      As[c4 + 0][row] = v.x; As[c4 + 1][row] = v.y; As[c4 + 2][row] = v.z; As[c4 + 3][row] = v.w;
    }
#pragma unroll
    for (int l = 0; l < 2; l++) {
      int idx = tid + l * 256; int row = idx >> 3, c4 = (idx & 7) << 2;
      float4 v = *(const float4*)(pW + (long)(n0 + row) * ldw + kb + c4);
      Bs[c4 + 0][row] = v.x; Bs[c4 + 1][row] = v.y; Bs[c4 + 2][row] = v.z; Bs[c4 + 3][row] = v.w;
    }
    __syncthreads();
#pragma unroll
    for (int k = 0; k < 32; k++) {
      float4 a = *(const float4*)&As[k][tm << 2];
      float4 b = *(const float4*)&Bs[k][tn << 2];
      FMA44(a, b, acc);
    }
    __syncthreads();
  }
#pragma unroll
  for (int r = 0; r < 4; r++) {
    int m = m0 + (tm << 2) + r;
#pragma unroll
    for (int c = 0; c < 4; c++) {
      int n = n0 + (tn << 2) + c;
      float v = acc[r][c];
      if (bias) v += bias[(long)gw * b_gs + n];
      if (ACT == 1) v = fmaxf(v, 0.f);
      if (OUTBF) ((__hip_bfloat16*)Cv)[(long)g * c_gs + (long)m * ldc + n] = __float2bfloat16(v);
      else       ((float*)Cv)[(long)g * c_gs + (long)m * ldc + n] = v;
    }
  }
}

// ---------------- MFMA bf16 two-segment grouped GEMM ----------------
// Same contract as gemm2seg, but computes in bf16 MFMA with f32 accum.
// C[g][m][n] = act( sum_k [A0|A1][ga][m][k] * W[gw][n][wofs+k] + bias[gw][n] )
// Tile 64x64, 4 waves (2x2), each wave 32x32 = 2x2 of 16x16x32 fragments.
// A/B fragment: lane l -> row/col (l&15), k = 8*(l>>4)+[0..7].
// C/D fragment: col = lane&15, row = (lane>>4)*4 + reg.
template <int ACT, int OUTBF, int A0BF>
__global__ __launch_bounds__(256)
void gemmMF(const void* __restrict__ A0v, long a0_gs, int lda0, int K0,
            const float* __restrict__ A1, long a1_gs, int lda1, int K1,
            const float* __restrict__ W, long w_gs, int ldw, int wofs,
            const float* __restrict__ bias, long b_gs,
            void* __restrict__ Cv, long c_gs, int ldc, int gdiv) {
  const int g = blockIdx.z;
  const int ga = g / gdiv, gw = g % DD;
  const float* pW = W + (long)gw * w_gs + wofs;
  const int m0 = blockIdx.x * 64, n0 = blockIdx.y * 64;
  const int tid = threadIdx.x;
  const int wave = tid >> 6, lane = tid & 63;
  const int wr = wave >> 1, wc = wave & 1;
  __shared__ short As[64][40];
  __shared__ short Bs[64][40];
  f32x4 acc[2][2];
#pragma unroll
  for (int a = 0; a < 2; a++)
#pragma unroll
    for (int b = 0; b < 2; b++) acc[a][b] = (f32x4)(0.f);
  const int K = K0 + K1;
  const int srow = tid >> 2;          // 0..63
  const int sks  = (tid & 3) << 3;    // 0,8,16,24
  for (int kb = 0; kb < K; kb += 32) {
    // stage A (f32->bf16 or direct bf16)
    {
      bf16x8 st;
      if (kb < K0) {
        if (A0BF) {
          const short* p = (const short*)A0v + (long)ga * a0_gs + (long)(m0 + srow) * lda0 + kb + sks;
          st = *(const bf16x8*)p;
        } else {
          const float* p = (const float*)A0v + (long)ga * a0_gs + (long)(m0 + srow) * lda0 + kb + sks;
          float4 v0 = *(const float4*)p, v1 = *(const float4*)(p + 4);
          st[0]=f2b(v0.x); st[1]=f2b(v0.y); st[2]=f2b(v0.z); st[3]=f2b(v0.w);
          st[4]=f2b(v1.x); st[5]=f2b(v1.y); st[6]=f2b(v1.z); st[7]=f2b(v1.w);
        }
      } else {
        const float* p = A1 + (long)ga * a1_gs + (long)(m0 + srow) * lda1 + (kb - K0) + sks;
        float4 v0 = *(const float4*)p, v1 = *(const float4*)(p + 4);
        st[0]=f2b(v0.x); st[1]=f2b(v0.y); st[2]=f2b(v0.z); st[3]=f2b(v0.w);
        st[4]=f2b(v1.x); st[5]=f2b(v1.y); st[6]=f2b(v1.z); st[7]=f2b(v1.w);
      }
      *(bf16x8*)&As[srow][sks] = st;
    }
    // stage B (weights f32->bf16)
    {
      const float* p = pW + (long)(n0 + srow) * ldw + kb + sks;
      float4 v0 = *(const float4*)p, v1 = *(const float4*)(p + 4);
      bf16x8 st;
      st[0]=f2b(v0.x); st[1]=f2b(v0.y); st[2]=f2b(v0.z); st[3]=f2b(v0.w);
      st[4]=f2b(v1.x); st[5]=f2b(v1.y); st[6]=f2b(v1.z); st[7]=f2b(v1.w);
      *(bf16x8*)&Bs[srow][sks] = st;
    }
    __syncthreads();
    {
      const int l15 = lane & 15, kq = (lane >> 4) << 3;
      bf16x8 a0 = *(const bf16x8*)&As[wr * 32 + l15][kq];
      bf16x8 a1 = *(const bf16x8*)&As[wr * 32 + 16 + l15][kq];
      bf16x8 b0 = *(const bf16x8*)&Bs[wc * 32 + l15][kq];
      bf16x8 b1 = *(const bf16x8*)&Bs[wc * 32 + 16 + l15][kq];
      acc[0][0] = __builtin_amdgcn_mfma_f32_16x16x32_bf16(a0, b0, acc[0][0], 0, 0, 0);
      acc[0][1] = __builtin_amdgcn_mfma_f32_16x16x32_bf16(a0, b1, acc[0][1], 0, 0, 0);
      acc[1][0] = __builtin_amdgcn_mfma_f32_16x16x32_bf16(a1, b0, acc[1][0], 0, 0, 0);
      acc[1][1] = __builtin_amdgcn_mfma_f32_16x16x32_bf16(a1, b1, acc[1][1], 0, 0, 0);
    }
    __syncthreads();
  }
  // epilogue
  const int ccol = lane & 15, crow4 = (lane >> 4) << 2;
#pragma unroll
  for (int mr = 0; mr < 2; mr++) {
#pragma unroll
    for (int nc = 0; nc < 2; nc++) {
      int n = n0 + wc * 32 + nc * 16 + ccol;
      float bv = bias ? bias[(long)gw * b_gs + n] : 0.f;
#pragma unroll
      for (int r = 0; r < 4; r++) {
        int m = m0 + wr * 32 + mr * 16 + crow4 + r;
        float v = acc[mr][nc][r] + bv;
        if (ACT == 1) v = fmaxf(v, 0.f);
        if (OUTBF) ((__hip_bfloat16*)Cv)[(long)g * c_gs + (long)m * ldc + n] = __float2bfloat16(v);
        else       ((float*)Cv)[(long)g * c_gs + (long)m * ldc + n] = v;
      }
    }
  }
}

// ---------------- GRU step ----------------
__global__ __launch_bounds__(256)
void k_gru(const float* __restrict__ GI, const float* __restrict__ hprev,
           const float* __restrict__ Whh, const float* __restrict__ bhh,
           float* __restrict__ hout, __hip_bfloat16* __restrict__ houtB) {
  const int bt = blockIdx.x >> 5, jt = blockIdx.x & 31;
  const int b0 = bt * 16, j0 = jt * 16;
  const int tid = threadIdx.x;
  const int bi = tid >> 4, ji = tid & 15;
  __shared__ float ws[48][132];
  __shared__ float hs[16][132];
  float ar = 0.f, az = 0.f, an = 0.f;
  for (int kc = 0; kc < HH; kc += 128) {
    for (int idx = tid; idx < 48 * 32; idx += 256) {
      int r = idx >> 5, c4 = (idx & 31) << 2;
      int jr = r / 3, gr = r % 3;
      int grow = gr * HH + j0 + jr;
      *(float4*)&ws[r][c4] = *(const float4*)(Whh + (long)grow * HH + kc + c4);
    }
    for (int idx = tid; idx < 16 * 32; idx += 256) {
      int r = idx >> 5, c4 = (idx & 31) << 2;
      float4 v;
      if (hprev) v = *(const float4*)(hprev + (long)(b0 + r) * HH + kc + c4);
      else { v.x = v.y = v.z = v.w = 0.f; }
      *(float4*)&hs[r][c4] = v;
    }
    __syncthreads();
    const int r0 = ji * 3;
    for (int k4 = 0; k4 < 128; k4 += 4) {
      float4 hv = *(const float4*)&hs[bi][k4];
      float4 w0 = *(const float4*)&ws[r0 + 0][k4];
      float4 w1 = *(const float4*)&ws[r0 + 1][k4];
      float4 w2 = *(const float4*)&ws[r0 + 2][k4];
      ar = fmaf(hv.x, w0.x, fmaf(hv.y, w0.y, fmaf(hv.z, w0.z, fmaf(hv.w, w0.w, ar))));
      az = fmaf(hv.x, w1.x, fmaf(hv.y, w1.y, fmaf(hv.z, w1.z, fmaf(hv.w, w1.w, az))));
      an = fmaf(hv.x, w2.x, fmaf(hv.y, w2.y, fmaf(hv.z, w2.z, fmaf(hv.w, w2.w, an))));
    }
    __syncthreads();
  }
  int j = j0 + ji, b = b0 + bi;
  float gr_ = ar + bhh[j], gz = az + bhh[HH + j], gn = an + bhh[2 * HH + j];
  const float* gi = GI + (long)b * G3;
  float ir = gi[j], iz = gi[HH + j], inn = gi[2 * HH + j];
  float r = 1.f / (1.f + expf(-(ir + gr_)));
  float zg = 1.f / (1.f + expf(-(iz + gz)));
  float n = tanhf(inn + r * gn);
  float hp = hprev ? hprev[(long)b * HH + j] : 0.f;
  float hnew = (1.f - zg) * n + zg * hp;
  hout[(long)b * HH + j] = hnew;
  if (houtB) houtB[(long)b * HH + j] = __float2bfloat16(hnew);
}

// ---------------- d-posterior (all experts) + kldc_e, chunked (f32 h input) ----------------
__global__ __launch_bounds__(256)
void k_dpa(const float* __restrict__ Wdp, const float* __restrict__ bdp,
           const float* __restrict__ HF, const float* __restrict__ LOGT,
           float* __restrict__ DPA, float* __restrict__ KCE, int t0) {
  const int tl = blockIdx.x; const int t = t0 + tl;
  const int bq = blockIdx.y; const int bb0 = bq * 32;
  const int tid = threadIdx.x;
  const int wv = tid >> 6;
  const int di = tid & 63; const int dd = di >> 3, ii = di & 7;
  __shared__ float obs[32][132];
  float acc[8];
#pragma unroll
  for (int r = 0; r < 8; r++) acc[r] = 0.f;
  for (int kc = 0; kc < HH; kc += 128) {
    for (int idx = tid; idx < 32 * 32; idx += 256) {
      int r = idx >> 5, c4 = (idx & 31) << 2;
      *(float4*)&obs[r][c4] = *(const float4*)(HF + ((long)tl * BB + bb0 + r) * HH + kc + c4);
    }
    __syncthreads();
    const float* wr = Wdp + (long)di * HH + kc;
    for (int k = 0; k < 128; k += 4) {
      float4 w4 = *(const float4*)(wr + k);
#pragma unroll
      for (int r = 0; r < 8; r++) {
        int bl = r * 4 + wv;
        float4 o4 = *(const float4*)&obs[bl][k];
        acc[r] = fmaf(o4.x, w4.x, fmaf(o4.y, w4.y, fmaf(o4.z, w4.z, fmaf(o4.w, w4.w, acc[r]))));
      }
    }
    __syncthreads();
  }
  float bsum = bdp[di];
#pragma unroll
  for (int r = 0; r < 8; r++) {
    int bl = r * 4 + wv; int b = bb0 + bl;
    float v = acc[r] + bsum;
    float mx = v;
    for (int m = 1; m < 8; m <<= 1) mx = fmaxf(mx, __shfl_xor(mx, m, 64));
    float e = expf(v - mx);
    float sm = e;
    for (int m = 1; m < 8; m <<= 1) sm += __shfl_xor(sm, m, 64);
    float p = e / sm;
    DPA[(((long)t * BB + b) * DD + dd) * DD + ii] = p;
    float term = p * (logf(p + 1e-8f) - LOGT[dd * 8 + ii]);
    for (int m = 1; m < 8; m <<= 1) term += __shfl_xor(term, m, 64);
    if (ii == 0) KCE[((long)t * DD + dd) * BB + b] = term;
  }
}

// ---------------- sequential d-trajectory (tiny) ----------------
__global__ void k_dchain(const float* __restrict__ DPA, const uint2* __restrict__ K1s,
                         int* __restrict__ EIDX, float* __restrict__ DP) {
  int b = threadIdx.x;
  if (b >= BB) return;
  int e = EIDX[b];
  for (int t = 0; t < TT; t++) {
    uint2 k1 = K1s[t];
    const float* p = DPA + (((long)t * BB + b) * DD + e) * DD;
    float best = -1e30f; int bi = 0;
#pragma unroll
    for (int i = 0; i < DD; i++) {
      float pi = p[i];
      DP[((long)(t + 1) * BB + b) * DD + i] = pi;
      float sc = logf(pi) + gumbelf(rbits(k1, b * DD + i, BB * DD));
      if (sc > best) { best = sc; bi = i; }
    }
    e = bi;
    EIDX[(t + 1) * BB + b] = e;
  }
}

// ---------------- fused sequential scan step ----------------
__global__ __launch_bounds__(256)
void k_step(int t, const int* __restrict__ EIDX, const uint2* __restrict__ K2s,
            const __hip_bfloat16* __restrict__ OBPc,
            const float* __restrict__ Wq1, const float* __restrict__ bq1,
            const float* __restrict__ Wq2, const float* __restrict__ bq2,
            const float* __restrict__ Wqm, const float* __restrict__ bqm,
            const float* __restrict__ Wqs, const float* __restrict__ bqs,
            float* __restrict__ ZT) {
  const int d = blockIdx.x & 7, bt = blockIdx.x >> 3;
  const int b0 = bt * 8;
  const int tid = threadIdx.x;
  __shared__ float zt_s[256][8];
  __shared__ float h1t[256][8];
  __shared__ float h2t[256][8];
  __shared__ int en_s[8];
  for (int i = tid; i < 8 * 256; i += 256) {
    int bl = i >> 8, k = i & 255;
    zt_s[k][bl] = ZT[((long)t * BB + b0 + bl) * ZZ + k];
  }
  if (tid < 8) en_s[tid] = EIDX[(t + 1) * BB + b0 + tid];
  __syncthreads();
  // phase 1: h1 = relu(OBPc + Wq1z @ z_prev + bq1)
  {
    const int j = tid;
    const float* wr = Wq1 + ((long)(d * ZZ + j)) * 768 + 512;
    const __hip_bfloat16* obr = OBPc + (((long)d * TC + (t & (TC - 1))) * BB + b0) * ZZ + j;
    float bj = bq1[d * ZZ + j];
    float acc[8];
#pragma unroll
    for (int bl = 0; bl < 8; bl++) acc[bl] = bj + __bfloat162float(obr[bl * ZZ]);
    for (int k = 0; k < ZZ; k += 4) {
      float4 w4 = *(const float4*)(wr + k);
      float4 z0, z1;
      z0 = *(const float4*)&zt_s[k + 0][0]; z1 = *(const float4*)&zt_s[k + 0][4]; FMA8M(z0, z1, w4.x, acc);
      z0 = *(const float4*)&zt_s[k + 1][0]; z1 = *(const float4*)&zt_s[k + 1][4]; FMA8M(z0, z1, w4.y, acc);
      z0 = *(const float4*)&zt_s[k + 2][0]; z1 = *(const float4*)&zt_s[k + 2][4]; FMA8M(z0, z1, w4.z, acc);
      z0 = *(const float4*)&zt_s[k + 3][0]; z1 = *(const float4*)&zt_s[k + 3][4]; FMA8M(z0, z1, w4.w, acc);
    }
#pragma unroll
    for (int bl = 0; bl < 8; bl++) h1t[j][bl] = fmaxf(acc[bl], 0.f);
  }
  __syncthreads();
  // phase 2: h2 = relu(Wq2 @ h1 + bq2)
  {
    const int j = tid;
    const float* wr = Wq2 + ((long)(d * ZZ + j)) * ZZ;
    float bj = bq2[d * ZZ + j];
    float acc[8];
#pragma unroll
    for (int bl = 0; bl < 8; bl++) acc[bl] = bj;
    for (int k = 0; k < ZZ; k += 4) {
      float4 w4 = *(const float4*)(wr + k);
      float4 z0, z1;
      z0 = *(const float4*)&h1t[k + 0][0]; z1 = *(const float4*)&h1t[k + 0][4]; FMA8M(z0, z1, w4.x, acc);
      z0 = *(const float4*)&h1t[k + 1][0]; z1 = *(const float4*)&h1t[k + 1][4]; FMA8M(z0, z1, w4.y, acc);
      z0 = *(const float4*)&h1t[k + 2][0]; z1 = *(const float4*)&h1t[k + 2][4]; FMA8M(z0, z1, w4.z, acc);
      z0 = *(const float4*)&h1t[k + 3][0]; z1 = *(const float4*)&h1t[k + 3][4]; FMA8M(z0, z1, w4.w, acc);
    }
#pragma unroll
    for (int bl = 0; bl < 8; bl++) h2t[j][bl] = fmaxf(acc[bl], 0.f);
  }
  __syncthreads();
  // phase 3: heads qm / qs(raw)
  float qm[8], qs[8];
  {
    const int j = tid;
    const float* wm = Wqm + ((long)(d * ZZ + j)) * ZZ;
    const float* wsd = Wqs + ((long)(d * ZZ + j)) * ZZ;
    float bm_ = bqm[d * ZZ + j], bs__ = bqs[d * ZZ + j];
#pragma unroll
    for (int bl = 0; bl < 8; bl++) { qm[bl] = bm_; qs[bl] = bs__; }
    for (int k = 0; k < ZZ; k += 4) {
      float4 wm4 = *(const float4*)(wm + k);
      float4 ws4 = *(const float4*)(wsd + k);
#pragma unroll
      for (int kk = 0; kk < 4; kk++) {
        float wmv = kk == 0 ? wm4.x : kk == 1 ? wm4.y : kk == 2 ? wm4.z : wm4.w;
        float wsv = kk == 0 ? ws4.x : kk == 1 ? ws4.y : kk == 2 ? ws4.z : ws4.w;
        float4 h0 = *(const float4*)&h2t[k + kk][0];
        float4 h1v = *(const float4*)&h2t[k + kk][4];
        FMA8M(h0, h1v, wmv, qm);
        FMA8M(h0, h1v, wsv, qs);
      }
    }
  }
  // phase 4: z sample (only block with matching expert writes)
#pragma unroll
  for (int bl = 0; bl < 8; bl++) {
    if (en_s[bl] == d) {
      int b = b0 + bl;
      float eps = normalf(rbits(K2s[t], b * ZZ + tid, BB * ZZ));
      ZT[((long)(t + 1) * BB + b) * ZZ + tid] = qm[bl] + softplusf_(qs[bl]) * eps;
    }
  }
}

// ---------------- loss-pass heads + reductions ----------------
__global__ __launch_bounds__(256)
void k_heads_pq(const float* __restrict__ LA, const float* __restrict__ LB,
                const float* __restrict__ Wpm, const float* __restrict__ bpm,
                const float* __restrict__ Wps, const float* __restrict__ bps,
                const float* __restrict__ Wqm, const float* __restrict__ bqm,
                const float* __restrict__ Wqs, const float* __restrict__ bqs,
                const float* __restrict__ DP, float* __restrict__ PART, int t0) {
  const int g = blockIdx.z; const int tl = g >> 3, d = g & 7; const int t = t0 + tl;
  const int m0 = blockIdx.x * 64, n0 = blockIdx.y * 64;
  const int tid = threadIdx.x; const int tm = tid >> 4, tn = tid & 15;
  __shared__ float As[32][68], W1s[32][68], W2s[32][68];
  float aPm[4][4], aPs[4][4], aQm[4][4], aQs[4][4];
#pragma unroll
  for (int r = 0; r < 4; r++)
#pragma unroll
    for (int c = 0; c < 4; c++) { aPm[r][c] = 0.f; aPs[r][c] = 0.f; aQm[r][c] = 0.f; aQs[r][c] = 0.f; }

#define HEADPASS(Abase, Wm_, Ws_, ACCM, ACCS) \
  { const float* Ap = (Abase) + (long)g * (BB * ZZ); \
    const float* Wm = (Wm_) + (long)d * ZZ * ZZ; \
    const float* Wsp = (Ws_) + (long)d * ZZ * ZZ; \
    for (int kb = 0; kb < ZZ; kb += 32) { \
      for (int l = 0; l < 2; l++) { \
        int idx = tid + l * 256; int row = idx >> 3, c4 = (idx & 7) << 2; \
        float4 v = *(const float4*)(Ap + (long)(m0 + row) * ZZ + kb + c4); \
        As[c4+0][row]=v.x; As[c4+1][row]=v.y; As[c4+2][row]=v.z; As[c4+3][row]=v.w; \
        v = *(const float4*)(Wm + (long)(n0 + row) * ZZ + kb + c4); \
        W1s[c4+0][row]=v.x; W1s[c4+1][row]=v.y; W1s[c4+2][row]=v.z; W1s[c4+3][row]=v.w; \
        v = *(const float4*)(Wsp + (long)(n0 + row) * ZZ + kb + c4); \
        W2s[c4+0][row]=v.x; W2s[c4+1][row]=v.y; W2s[c4+2][row]=v.z; W2s[c4+3][row]=v.w; \
      } \
      __syncthreads(); \
      _Pragma("unroll") \
      for (int k = 0; k < 32; k++) { \
        float4 a = *(const float4*)&As[k][tm << 2]; \
        float4 b1 = *(const float4*)&W1s[k][tn << 2]; \
        float4 b2 = *(const float4*)&W2s[k][tn << 2]; \
        FMA44(a, b1, ACCM); \
        FMA44(a, b2, ACCS); \
      } \
      __syncthreads(); \
    } }

  HEADPASS(LA, Wpm, Wps, aPm, aPs)
  HEADPASS(LB, Wqm, Wqs, aQm, aQs)

  float local = 0.f;
#pragma unroll
  for (int r = 0; r < 4; r++) {
    int b = m0 + (tm << 2) + r;
    float w8 = DP[((long)(t + 1) * BB + b) * DD + d];
#pragma unroll
    for (int c = 0; c < 4; c++) {
      int n = n0 + (tn << 2) + c;
      float pm = aPm[r][c] + bpm[d * ZZ + n];
      float ps = softplusf_(aPs[r][c] + bps[d * ZZ + n]);
      float qm = aQm[r][c] + bqm[d * ZZ + n];
      float qs = softplusf_(aQs[r][c] + bqs[d * ZZ + n]);
      float dm = qm - pm;
      local += 0.5f * w8 * (2.f * logf(ps / qs) + (qs * qs + dm * dm) / (ps * ps) - 1.f);
    }
  }
  local = wave_sum(local);
  __shared__ float red[4];
  int wid = tid >> 6;
  if ((tid & 63) == 0) red[wid] = local;
  __syncthreads();
  if (tid == 0) atomicAdd(&PART[((long)t * DD + d) * 4 + 0], red[0] + red[1] + red[2] + red[3]);
}

__global__ __launch_bounds__(256)
void k_heads_e(const float* __restrict__ LA,
               const float* __restrict__ Wem, const float* __restrict__ bem,
               const float* __restrict__ Wes, const float* __restrict__ bes,
               const float* __restrict__ yy, const float* __restrict__ DP,
               const float* __restrict__ KCE, float* __restrict__ PART, int t0) {
  const int g = blockIdx.z; const int tl = g >> 3, d = g & 7; const int t = t0 + tl;
  const int m0 = blockIdx.x * 64, n0 = blockIdx.y * 64;
  const int tid = threadIdx.x; const int tm = tid >> 4, tn = tid & 15;
  __shared__ float As[32][68], W1s[32][68], W2s[32][68];
  float aM[4][4], aS[4][4];
#pragma unroll
  for (int r = 0; r < 4; r++)
#pragma unroll
    for (int c = 0; c < 4; c++) { aM[r][c] = 0.f; aS[r][c] = 0.f; }
  {
    const float* Ap = LA + (long)g * (BB * ZZ);
    const float* Wm = Wem + (long)d * YY * YY;
    const float* Wsp = Wes + (long)d * YY * YY;
    for (int kb = 0; kb < YY; kb += 32) {
      for (int l = 0; l < 2; l++) {
        int idx = tid + l * 256; int row = idx >> 3, c4 = (idx & 7) << 2;
        float4 v = *(const float4*)(Ap + (long)(m0 + row) * YY + kb + c4);
        As[c4+0][row]=v.x; As[c4+1][row]=v.y; As[c4+2][row]=v.z; As[c4+3][row]=v.w;
        v = *(const float4*)(Wm + (long)(n0 + row) * YY + kb + c4);
        W1s[c4+0][row]=v.x; W1s[c4+1][row]=v.y; W1s[c4+2][row]=v.z; W1s[c4+3][row]=v.w;
        v = *(const float4*)(Wsp + (long)(n0 + row) * YY + kb + c4);
        W2s[c4+0][row]=v.x; W2s[c4+1][row]=v.y; W2s[c4+2][row]=v.z; W2s[c4+3][row]=v.w;
      }
      __syncthreads();
#pragma unroll
      for (int k = 0; k < 32; k++) {
        float4 a = *(const float4*)&As[k][tm << 2];
        float4 b1 = *(const float4*)&W1s[k][tn << 2];
        float4 b2 = *(const float4*)&W2s[k][tn << 2];
        FMA44(a, b1, aM);
        FMA44(a, b2, aS);
      }
      __syncthreads();
    }
  }
  float local = 0.f;
#pragma unroll
  for (int r = 0; r < 4; r++) {
    int b = m0 + (tm << 2) + r;
    float w8 = DP[((long)(t + 1) * BB + b) * DD + d];
#pragma unroll
    for (int c = 0; c < 4; c++) {
      int n = n0 + (tn << 2) + c;
      float ym = aM[r][c] + bem[d * YY + n];
      float ys = softplusf_(aS[r][c] + bes[d * YY + n]);
      float yv = yy[((long)t * BB + b) * YY + n];
      float rr = (yv - ym) / ys;
      local += w8 * 0.5f * (1.8378770664093453f + 2.f * logf(ys) + rr * rr);
    }
  }
  local = wave_sum(local);
  __shared__ float red[4];
  int wid = tid >> 6;
  if ((tid & 63) == 0) red[wid] = local;
  __syncthreads();
  if (tid == 0) atomicAdd(&PART[((long)t * DD + d) * 4 + 2], red[0] + red[1] + red[2] + red[3]);
  if (blockIdx.x == 0 && blockIdx.y == 0) {
    __syncthreads();
    float v = 0.f;
    if (tid < BB) v = KCE[((long)t * DD + d) * BB + tid] * DP[((long)t * BB + tid) * DD + d];
    v = wave_sum(v);
    if ((tid & 63) == 0) red[wid] = v;
    __syncthreads();
    if (tid == 0) atomicAdd(&PART[((long)t * DD + d) * 4 + 1], red[0] + red[1] + red[2] + red[3]);
  }
}

__global__ void k_fin(const float* __restrict__ PART, float* __restrict__ out) {
  int tid = threadIdx.x;
  float s0 = 0.f, s1 = 0.f, s2 = 0.f;
  for (int i = tid; i < TT * DD; i += 256) {
    s0 += PART[i * 4 + 0]; s1 += PART[i * 4 + 1]; s2 += PART[i * 4 + 2];
  }
  s0 = wave_sum(s0); s1 = wave_sum(s1); s2 = wave_sum(s2);
  __shared__ float r0[4], r1[4], r2[4];
  int wid = tid >> 6;
  if ((tid & 63) == 0) { r0[wid] = s0; r1[wid] = s1; r2[wid] = s2; }
  __syncthreads();
  if (tid == 0) {
    out[0] = r0[0] + r0[1] + r0[2] + r0[3];
    out[1] = r1[0] + r1[1] + r1[2] + r1[3];
    out[2] = r2[0] + r2[1] + r2[2] + r2[3];
  }
}

// ---------------- host launcher ----------------
extern "C" void kernel_launch(void* const* d_in, const int* in_sizes, int n_in,
                              void* d_out, int out_size, void* d_ws, size_t ws_size,
                              hipStream_t stream) {
  (void)in_sizes; (void)n_in; (void)out_size;
  const float* x      = (const float*)d_in[0];
  const float* y      = (const float*)d_in[1];
  const float* Wdpr   = (const float*)d_in[2];
  const float* bdpr   = (const float*)d_in[3];
  const float* Wdp    = (const float*)d_in[4];
  const float* bdp    = (const float*)d_in[5];
  const float* Wq1    = (const float*)d_in[6];
  const float* bq1    = (const float*)d_in[7];
  const float* Wq2    = (const float*)d_in[8];
  const float* bq2    = (const float*)d_in[9];
  const float* Wqm    = (const float*)d_in[10];
  const float* bqm    = (const float*)d_in[11];
  const float* Wqs    = (const float*)d_in[12];
  const float* bqs    = (const float*)d_in[13];
  const float* Wp1    = (const float*)d_in[14];
  const float* bp1    = (const float*)d_in[15];
  const float* Wp2    = (const float*)d_in[16];
  const float* bp2    = (const float*)d_in[17];
  const float* Wpm    = (const float*)d_in[18];
  const float* bpm    = (const float*)d_in[19];
  const float* Wps    = (const float*)d_in[20];
  const float* bps    = (const float*)d_in[21];
  const float* We1    = (const float*)d_in[22];
  const float* be1    = (const float*)d_in[23];
  const float* We2    = (const float*)d_in[24];
  const float* be2    = (const float*)d_in[25];
  const float* Wem    = (const float*)d_in[26];
  const float* bem    = (const float*)d_in[27];
  const float* Wes    = (const float*)d_in[28];
  const float* bes    = (const float*)d_in[29];
  const float* Wih_f  = (const float*)d_in[30];
  const float* Whh_f  = (const float*)d_in[31];
  const float* bih_f  = (const float*)d_in[32];
  const float* bhh_f  = (const float*)d_in[33];
  const float* Wih_b  = (const float*)d_in[34];
  const float* Whh_b  = (const float*)d_in[35];
  const float* bih_b  = (const float*)d_in[36];
  const float* bhh_b  = (const float*)d_in[37];

  char* base = (char*)d_ws;
  size_t off = 0;
  auto alloc = [&](size_t bytes) -> char* {
    char* p = base + off;
    off += (bytes + 1023) & ~(size_t)1023;
    return p;
  };
  float* LOGT = (float*)alloc(64 * 4);
  uint2* KEYS = (uint2*)alloc(TT * 8);
  uint2* K1s  = (uint2*)alloc(TT * 8);
  uint2* K2s  = (uint2*)alloc(TT * 8);
  int*   EIDX = (int*)alloc((size_t)(TT + 1) * BB * 4);
  float* DP   = (float*)alloc((size_t)(TT + 1) * BB * DD * 4);
  float* DPA  = (float*)alloc((size_t)TT * BB * DD * DD * 4);
  float* KCE  = (float*)alloc((size_t)TT * DD * BB * 4);
  float* ZT   = (float*)alloc((size_t)(TT + 1) * BB * ZZ * 4);
  float* PART = (float*)alloc((size_t)TT * DD * 4 * 4);
  float* OF   = (float*)alloc((size_t)TT * BB * HH * 4);          // f32 (d-path fidelity + loss)
  __hip_bfloat16* OB = (__hip_bfloat16*)alloc((size_t)TT * BB * HH * 2);  // bf16 (z-path/loss only)
  float* HROLL = (float*)alloc((size_t)TC * BB * HH * 4);         // f32 rolling backward h
  char*  SH   = alloc((size_t)TC * BB * G3 * 4);                  // 25.2MB shared region
  float* GIc  = (float*)SH;
  __hip_bfloat16* OBPc = (__hip_bfloat16*)SH;
  float* LH1  = (float*)SH;
  float* LH2A = LH1 + (size_t)CH * DD * BB * ZZ;
  float* LH2B = LH2A + (size_t)CH * DD * BB * ZZ;

  if (ws_size < off) {   // workspace too small: emit sentinel instead of faulting
    k_sentinel<<<1, 64, 0, stream>>>((float*)d_out);
    return;
  }

  hipMemsetAsync(PART, 0, (size_t)TT * DD * 4 * 4, stream);
  k_init1<<<1, 256, 0, stream>>>(Wdpr, bdpr, LOGT, KEYS, K1s, K2s);
  k_init2<<<33, 256, 0, stream>>>(EIDX, DP, ZT);

  const long BH = (long)BB * HH, BZ = (long)BB * ZZ, BG = (long)BB * G3;

  // forward GRU, chunked input projection (f32 — feeds discrete d-path)
  for (int c = 0; c < TT / TC; c++) {
    int t0 = c * TC;
    gemm2seg<0, 0, 0><<<dim3(64, 24, 1), 256, 0, stream>>>(
        x + (long)t0 * BB * XX, 0, XX, XX, nullptr, 0, 4, 0,
        Wih_f, 0, XX, 0, bih_f, 0, GIc, 0, G3, 1);
    for (int tl = 0; tl < TC; tl++) {
      int t = t0 + tl;
      k_gru<<<256, 256, 0, stream>>>(GIc + (long)tl * BG,
                                     t ? (OF + (long)(t - 1) * BH) : nullptr,
                                     Whh_f, bhh_f, OF + (long)t * BH, nullptr);
    }
  }
  // backward GRU (reversed time), chunked; f32 h in HROLL, bf16 persist in OB
  for (int c = TT / TC - 1; c >= 0; c--) {
    int t0 = c * TC;
    gemm2seg<0, 0, 0><<<dim3(64, 24, 1), 256, 0, stream>>>(
        y + (long)t0 * BB * YY, 0, YY, YY, OF + (long)t0 * BH, 0, HH, HH,
        Wih_b, 0, 768, 0, bih_b, 0, GIc, 0, G3, 1);
    for (int tl = TC - 1; tl >= 0; tl--) {
      int t = t0 + tl;
      k_gru<<<256, 256, 0, stream>>>(GIc + (long)tl * BG,
                                     (t == TT - 1) ? nullptr : (HROLL + (long)((t + 1) & (TC - 1)) * BH),
                                     Whh_b, bhh_b, HROLL + (long)(t & (TC - 1)) * BH, OB + (long)t * BH);
    }
    k_dpa<<<dim3(TC, 4), 256, 0, stream>>>(Wdp, bdp, HROLL, LOGT, DPA, KCE, t0);
  }
  // sequential d-trajectory
  k_dchain<<<1, 128, 0, stream>>>(DPA, K1s, EIDX, DP);
  // z-scan, chunked OBP hoist (MFMA)
  for (int c = 0; c < TT / TC; c++) {
    int t0 = c * TC;
    gemmMF<0, 1, 1><<<dim3(64, 4, 8), 256, 0, stream>>>(
        OB + (long)t0 * BH, 0, HH, HH, nullptr, 0, 4, 0,
        Wq1, (long)ZZ * 768, 768, 0, nullptr, 0, OBPc, (long)TC * BB * ZZ, ZZ, 8);
    for (int tl = 0; tl < TC; tl++) {
      k_step<<<128, 256, 0, stream>>>(t0 + tl, EIDX, K2s, OBPc,
                                      Wq1, bq1, Wq2, bq2, Wqm, bqm, Wqs, bqs, ZT);
    }
  }
  // parallel loss pass, chunked over t (MFMA for the 6 MLP GEMMs)
  for (int c = 0; c < TT / CH; c++) {
    int t0 = c * CH;
    dim3 gl(2, 4, CH * DD);
    // p branch
    gemmMF<1, 0, 0><<<gl, 256, 0, stream>>>(
        OF + (long)t0 * BH, BH, HH, HH, ZT + (long)t0 * BZ, BZ, ZZ, ZZ,
        Wp1, (long)ZZ * 768, 768, 0, bp1, ZZ, LH1, BZ, ZZ, 8);
    gemmMF<1, 0, 0><<<gl, 256, 0, stream>>>(
        LH1, BZ, ZZ, ZZ, nullptr, 0, 4, 0,
        Wp2, (long)ZZ * ZZ, ZZ, 0, bp2, ZZ, LH2A, BZ, ZZ, 1);
    // q branch (A0 = OB bf16, K=768)
    gemmMF<1, 0, 1><<<gl, 256, 0, stream>>>(
        OB + (long)t0 * BH, BH, HH, HH, ZT + (long)t0 * BZ, BZ, ZZ, ZZ,
        Wq1, (long)ZZ * 768, 768, 0, bq1, ZZ, LH1, BZ, ZZ, 8);
    gemmMF<1, 0, 0><<<gl, 256, 0, stream>>>(
        LH1, BZ, ZZ, ZZ, nullptr, 0, 4, 0,
        Wq2, (long)ZZ * ZZ, ZZ, 0, bq2, ZZ, LH2B, BZ, ZZ, 1);
    k_heads_pq<<<gl, 256, 0, stream>>>(LH2A, LH2B, Wpm, bpm, Wps, bps,
                                       Wqm, bqm, Wqs, bqs, DP, PART, t0);
    // e branch
    gemmMF<1, 0, 0><<<gl, 256, 0, stream>>>(
        OF + (long)t0 * BH, BH, HH, HH, ZT + (long)(t0 + 1) * BZ, BZ, ZZ, ZZ,
        We1, (long)YY * 768, 768, 0, be1, YY, LH1, BZ, ZZ, 8);
    gemmMF<1, 0, 0><<<gl, 256, 0, stream>>>(
        LH1, BZ, ZZ, ZZ, nullptr, 0, 4, 0,
        We2, (long)YY * YY, YY, 0, be2, YY, LH2A, BZ, ZZ, 1);
    k_heads_e<<<gl, 256, 0, stream>>>(LH2A, Wem, bem, Wes, bes, y, DP, KCE, PART, t0);
  }
  k_fin<<<1, 256, 0, stream>>>(PART, (float*)d_out);
}

// Round 8
// 24103.391 us; speedup vs baseline: 1.3337x; 1.1225x over previous
//
#include <hip/hip_runtime.h>
#include <hip/hip_bf16.h>
#include <math.h>
#include <stdint.h>

#define TT 256
#define BB 128
#define XX 128
#define YY 256
#define HH 512
#define ZZ 256
#define DD 8
#define G3 1536
#define CH 8    // loss-pass t-chunk
#define TC 32   // GRU / scan t-chunk

typedef unsigned int u32;
typedef __attribute__((ext_vector_type(8))) short bf16x8;
typedef __attribute__((ext_vector_type(4))) float f32x4;

// ---------------- JAX threefry2x32 PRNG ----------------
__device__ __forceinline__ uint2 tf2(uint2 key, u32 c0, u32 c1) {
  u32 ks0 = key.x, ks1 = key.y, ks2 = ks0 ^ ks1 ^ 0x1BD11BDAu;
  u32 x0 = c0 + ks0, x1 = c1 + ks1;
#define TFR(r) { x0 += x1; x1 = (x1 << r) | (x1 >> (32 - r)); x1 ^= x0; }
  TFR(13) TFR(15) TFR(26) TFR(6)  x0 += ks1; x1 += ks2 + 1u;
  TFR(17) TFR(29) TFR(16) TFR(24) x0 += ks2; x1 += ks0 + 2u;
  TFR(13) TFR(15) TFR(26) TFR(6)  x0 += ks0; x1 += ks1 + 3u;
  TFR(17) TFR(29) TFR(16) TFR(24) x0 += ks1; x1 += ks2 + 4u;
  TFR(13) TFR(15) TFR(26) TFR(6)  x0 += ks2; x1 += ks0 + 5u;
#undef TFR
  uint2 r; r.x = x0; r.y = x1; return r;
}

__device__ __forceinline__ u32 rbits(uint2 key, int i, int n) {
  int h = n >> 1;
  if (i < h) return tf2(key, (u32)i, (u32)(i + h)).x;
  return tf2(key, (u32)(i - h), (u32)i).y;
}

__device__ __forceinline__ float unif(u32 bits, float mn, float mx) {
  float f = __uint_as_float((bits >> 9) | 0x3F800000u) - 1.0f;
  return fmaxf(mn, f * (mx - mn) + mn);
}

__device__ __forceinline__ float gumbelf(u32 bits) {
  float u = unif(bits, 1.17549435e-38f, 1.0f);
  return -logf(-logf(u));
}

__device__ __forceinline__ float erfinvf_x(float x) {
  float w = -log1pf(-x * x);
  float p;
  if (w < 5.0f) {
    w -= 2.5f;
    p = 2.81022636e-08f;
    p = fmaf(p, w, 3.43273939e-07f);
    p = fmaf(p, w, -3.5233877e-06f);
    p = fmaf(p, w, -4.39150654e-06f);
    p = fmaf(p, w, 0.00021858087f);
    p = fmaf(p, w, -0.00125372503f);
    p = fmaf(p, w, -0.00417768164f);
    p = fmaf(p, w, 0.246640727f);
    p = fmaf(p, w, 1.50140941f);
  } else {
    w = sqrtf(w) - 3.0f;
    p = -0.000200214257f;
    p = fmaf(p, w, 0.000100950558f);
    p = fmaf(p, w, 0.00134934322f);
    p = fmaf(p, w, -0.00367342844f);
    p = fmaf(p, w, 0.00573950773f);
    p = fmaf(p, w, -0.0076224613f);
    p = fmaf(p, w, 0.00943887047f);
    p = fmaf(p, w, 1.00167406f);
    p = fmaf(p, w, 2.83297682f);
  }
  return p * x;
}

__device__ __forceinline__ float normalf(u32 bits) {
  float u = unif(bits, -0.99999994f, 1.0f);
  return 1.41421356f * erfinvf_x(u);
}

__device__ __forceinline__ float softplusf_(float x) {
  return fmaxf(x, 0.0f) + log1pf(expf(-fabsf(x)));
}

__device__ __forceinline__ float wave_sum(float v) {
#pragma unroll
  for (int m = 1; m < 64; m <<= 1) v += __shfl_xor(v, m, 64);
  return v;
}

__device__ __forceinline__ float b2f(u32 h) { return __uint_as_float(h << 16); }

__device__ __forceinline__ short f2b(float f) {
  __hip_bfloat16 h = __float2bfloat16(f);
  return *reinterpret_cast<short*>(&h);
}

#define FMA8M(v0, v1, wv, A) do { \
  A[0]=fmaf((v0).x,(wv),A[0]); A[1]=fmaf((v0).y,(wv),A[1]); \
  A[2]=fmaf((v0).z,(wv),A[2]); A[3]=fmaf((v0).w,(wv),A[3]); \
  A[4]=fmaf((v1).x,(wv),A[4]); A[5]=fmaf((v1).y,(wv),A[5]); \
  A[6]=fmaf((v1).z,(wv),A[6]); A[7]=fmaf((v1).w,(wv),A[7]); } while(0)

#define FMA44(a4, b4, A) do { \
  A[0][0]=fmaf((a4).x,(b4).x,A[0][0]); A[0][1]=fmaf((a4).x,(b4).y,A[0][1]); A[0][2]=fmaf((a4).x,(b4).z,A[0][2]); A[0][3]=fmaf((a4).x,(b4).w,A[0][3]); \
  A[1][0]=fmaf((a4).y,(b4).x,A[1][0]); A[1][1]=fmaf((a4).y,(b4).y,A[1][1]); A[1][2]=fmaf((a4).y,(b4).z,A[1][2]); A[1][3]=fmaf((a4).y,(b4).w,A[1][3]); \
  A[2][0]=fmaf((a4).z,(b4).x,A[2][0]); A[2][1]=fmaf((a4).z,(b4).y,A[2][1]); A[2][2]=fmaf((a4).z,(b4).z,A[2][2]); A[2][3]=fmaf((a4).z,(b4).w,A[2][3]); \
  A[3][0]=fmaf((a4).w,(b4).x,A[3][0]); A[3][1]=fmaf((a4).w,(b4).y,A[3][1]); A[3][2]=fmaf((a4).w,(b4).z,A[3][2]); A[3][3]=fmaf((a4).w,(b4).w,A[3][3]); } while(0)

// ---------------- sentinel (workspace too small diagnostic) ----------------
__global__ void k_sentinel(float* __restrict__ out) {
  if (threadIdx.x < 3) out[threadIdx.x] = 1.2345e8f;
}

// ---------------- f32 -> bf16 weight conversion ----------------
__global__ void k_cvt(const float* __restrict__ s, __hip_bfloat16* __restrict__ d, int n4) {
  int i = blockIdx.x * 256 + threadIdx.x;
  int stride = gridDim.x * 256;
  for (; i < n4; i += stride) {
    const float4 v = *(const float4*)(s + (size_t)i * 4);
    short4 o; o.x = f2b(v.x); o.y = f2b(v.y); o.z = f2b(v.z); o.w = f2b(v.w);
    *(short4*)((short*)d + (size_t)i * 4) = o;
  }
}

// ---------------- init kernels ----------------
__global__ void k_init1(const float* __restrict__ Wdpr, const float* __restrict__ bdpr,
                        float* __restrict__ LOGT, uint2* __restrict__ KEYS,
                        uint2* __restrict__ K1s, uint2* __restrict__ K2s) {
  int tid = threadIdx.x;
  if (tid == 0) {
    uint2 key; key.x = 0u; key.y = 1u;   // jax.random.key(1)
    for (int t = 0; t < TT; t++) {
      KEYS[t] = key;
      uint2 e0 = tf2(key, 0u, 3u);
      uint2 e1 = tf2(key, 1u, 4u);
      key.x = e0.x; key.y = e1.x;        // split(key,3)[0]
    }
  }
  __syncthreads();
  for (int t = tid; t < TT; t += 256) {
    uint2 key = KEYS[t];
    uint2 e0 = tf2(key, 0u, 3u);
    uint2 e1 = tf2(key, 1u, 4u);
    uint2 e2 = tf2(key, 2u, 5u);
    uint2 k1; k1.x = e2.x; k1.y = e0.y;  // split[1]
    uint2 k2; k2.x = e1.y; k2.y = e2.y;  // split[2]
    K1s[t] = k1; K2s[t] = k2;
  }
  if (tid < 64) {
    int i = tid >> 3, j = tid & 7;
    float s = bdpr[j];
#pragma unroll
    for (int k = 0; k < 8; k++) s += ((k == i) ? 0.65f : 0.05f) * Wdpr[j * 8 + k];
    float mx = s;
    for (int m = 1; m < 8; m <<= 1) mx = fmaxf(mx, __shfl_xor(mx, m, 64));
    float e = expf(s - mx);
    float sm = e;
    for (int m = 1; m < 8; m <<= 1) sm += __shfl_xor(sm, m, 64);
    float tr = (e / sm) * 0.5f + ((i == j) ? 0.5f : 0.0f);
    LOGT[i * 8 + j] = logf(tr);
  }
}

__global__ void k_init2(int* __restrict__ EIDX, float* __restrict__ DP, float* __restrict__ ZT) {
  int blk = blockIdx.x, tid = threadIdx.x;
  if (blk == 0) {
    if (tid < BB) {
      uint2 k7; k7.x = 0u; k7.y = 7u;    // jax.random.key(7)
      float best = -1e30f; int bi = 0;
      for (int i = 0; i < DD; i++) {
        float g = gumbelf(rbits(k7, tid * DD + i, BB * DD));
        if (g > best) { best = g; bi = i; }
      }
      EIDX[tid] = bi;
      for (int i = 0; i < DD; i++) DP[tid * DD + i] = 0.125f;
    }
  } else {
    int base = (blk - 1) * 1024 + tid;
    ZT[base] = 0.f; ZT[base + 256] = 0.f; ZT[base + 512] = 0.f; ZT[base + 768] = 0.f;
  }
}

// ---------------- generic two-segment grouped GEMM (f32 VALU) ----------------
// kept for the d-path-critical gi projections (must stay f32)
template <int ACT, int OUTBF>
__global__ __launch_bounds__(256)
void gemm2seg(const float* __restrict__ A0, long a0_gs, int lda0, int K0,
              const float* __restrict__ A1, long a1_gs, int lda1, int K1,
              const float* __restrict__ W, long w_gs, int ldw, int wofs,
              const float* __restrict__ bias, long b_gs,
              void* __restrict__ Cv, long c_gs, int ldc, int gdiv) {
  const int g = blockIdx.z;
  const int ga = g / gdiv, gw = g % DD;
  const float* pW = W + (long)gw * w_gs + wofs;
  const int m0 = blockIdx.x * 64, n0 = blockIdx.y * 64;
  const int tid = threadIdx.x;
  const int tm = tid >> 4, tn = tid & 15;
  __shared__ float As[32][68];
  __shared__ float Bs[32][68];
  float acc[4][4];
#pragma unroll
  for (int r = 0; r < 4; r++)
#pragma unroll
    for (int c = 0; c < 4; c++) acc[r][c] = 0.f;
  const int K = K0 + K1;
  for (int kb = 0; kb < K; kb += 32) {
#pragma unroll
    for (int l = 0; l < 2; l++) {
      int idx = tid + l * 256; int row = idx >> 3, c4 = (idx & 7) << 2;
      float4 v;
      if (kb < K0) {
        v = *(const float4*)(A0 + (long)ga * a0_gs + (long)(m0 + row) * lda0 + kb + c4);
      } else {
        v = *(const float4*)(A1 + (long)ga * a1_gs + (long)(m0 + row) * lda1 + (kb - K0) + c4);
      }
      As[c4 + 0][row] = v.x; As[c4 + 1][row] = v.y; As[c4 + 2][row] = v.z; As[c4 + 3][row] = v.w;
    }
#pragma unroll
    for (int l = 0; l < 2; l++) {
      int idx = tid + l * 256; int row = idx >> 3, c4 = (idx & 7) << 2;
      float4 v = *(const float4*)(pW + (long)(n0 + row) * ldw + kb + c4);
      Bs[c4 + 0][row] = v.x; Bs[c4 + 1][row] = v.y; Bs[c4 + 2][row] = v.z; Bs[c4 + 3][row] = v.w;
    }
    __syncthreads();
#pragma unroll
    for (int k = 0; k < 32; k++) {
      float4 a = *(const float4*)&As[k][tm << 2];
      float4 b = *(const float4*)&Bs[k][tn << 2];
      FMA44(a, b, acc);
    }
    __syncthreads();
  }
#pragma unroll
  for (int r = 0; r < 4; r++) {
    int m = m0 + (tm << 2) + r;
#pragma unroll
    for (int c = 0; c < 4; c++) {
      int n = n0 + (tn << 2) + c;
      float v = acc[r][c];
      if (bias) v += bias[(long)gw * b_gs + n];
      if (ACT == 1) v = fmaxf(v, 0.f);
      if (OUTBF) ((__hip_bfloat16*)Cv)[(long)g * c_gs + (long)m * ldc + n] = __float2bfloat16(v);
      else       ((float*)Cv)[(long)g * c_gs + (long)m * ldc + n] = v;
    }
  }
}

// ---------------- MFMA bf16 two-segment grouped GEMM (bf16 weights) ----------------
// C[g][m][n] = act( sum_k [A0|A1][ga][m][k] * W[gw][n][wofs+k] + bias[gw][n] )
// Tile 64x64, 4 waves (2x2); A/B frag: lane l -> row/col (l&15), k=8*(l>>4)+[0..7];
// C/D frag: col = lane&15, row = (lane>>4)*4 + reg.
template <int ACT, int OUTBF, int A0BF>
__global__ __launch_bounds__(256)
void gemmMF(const void* __restrict__ A0v, long a0_gs, int lda0, int K0,
            const float* __restrict__ A1, long a1_gs, int lda1, int K1,
            const __hip_bfloat16* __restrict__ W, long w_gs, int ldw, int wofs,
            const float* __restrict__ bias, long b_gs,
            void* __restrict__ Cv, long c_gs, int ldc, int gdiv) {
  const int g = blockIdx.z;
  const int ga = g / gdiv, gw = g % DD;
  const short* pW = (const short*)W + (long)gw * w_gs + wofs;
  const int m0 = blockIdx.x * 64, n0 = blockIdx.y * 64;
  const int tid = threadIdx.x;
  const int wave = tid >> 6, lane = tid & 63;
  const int wr = wave >> 1, wc = wave & 1;
  __shared__ short As[64][40];
  __shared__ short Bs[64][40];
  f32x4 acc[2][2];
#pragma unroll
  for (int a = 0; a < 2; a++)
#pragma unroll
    for (int b = 0; b < 2; b++) acc[a][b] = (f32x4)(0.f);
  const int K = K0 + K1;
  const int srow = tid >> 2;          // 0..63
  const int sks  = (tid & 3) << 3;    // 0,8,16,24
  for (int kb = 0; kb < K; kb += 32) {
    // stage A (bf16 direct or f32->bf16)
    {
      bf16x8 st;
      if (kb < K0) {
        if (A0BF) {
          const short* p = (const short*)A0v + (long)ga * a0_gs + (long)(m0 + srow) * lda0 + kb + sks;
          st = *(const bf16x8*)p;
        } else {
          const float* p = (const float*)A0v + (long)ga * a0_gs + (long)(m0 + srow) * lda0 + kb + sks;
          float4 v0 = *(const float4*)p, v1 = *(const float4*)(p + 4);
          st[0]=f2b(v0.x); st[1]=f2b(v0.y); st[2]=f2b(v0.z); st[3]=f2b(v0.w);
          st[4]=f2b(v1.x); st[5]=f2b(v1.y); st[6]=f2b(v1.z); st[7]=f2b(v1.w);
        }
      } else {
        const float* p = A1 + (long)ga * a1_gs + (long)(m0 + srow) * lda1 + (kb - K0) + sks;
        float4 v0 = *(const float4*)p, v1 = *(const float4*)(p + 4);
        st[0]=f2b(v0.x); st[1]=f2b(v0.y); st[2]=f2b(v0.z); st[3]=f2b(v0.w);
        st[4]=f2b(v1.x); st[5]=f2b(v1.y); st[6]=f2b(v1.z); st[7]=f2b(v1.w);
      }
      *(bf16x8*)&As[srow][sks] = st;
    }
    // stage B (bf16 weights, direct copy)
    *(bf16x8*)&Bs[srow][sks] = *(const bf16x8*)(pW + (long)(n0 + srow) * ldw + kb + sks);
    __syncthreads();
    {
      const int l15 = lane & 15, kq = (lane >> 4) << 3;
      bf16x8 a0 = *(const bf16x8*)&As[wr * 32 + l15][kq];
      bf16x8 a1 = *(const bf16x8*)&As[wr * 32 + 16 + l15][kq];
      bf16x8 b0 = *(const bf16x8*)&Bs[wc * 32 + l15][kq];
      bf16x8 b1 = *(const bf16x8*)&Bs[wc * 32 + 16 + l15][kq];
      acc[0][0] = __builtin_amdgcn_mfma_f32_16x16x32_bf16(a0, b0, acc[0][0], 0, 0, 0);
      acc[0][1] = __builtin_amdgcn_mfma_f32_16x16x32_bf16(a0, b1, acc[0][1], 0, 0, 0);
      acc[1][0] = __builtin_amdgcn_mfma_f32_16x16x32_bf16(a1, b0, acc[1][0], 0, 0, 0);
      acc[1][1] = __builtin_amdgcn_mfma_f32_16x16x32_bf16(a1, b1, acc[1][1], 0, 0, 0);
    }
    __syncthreads();
  }
  // epilogue
  const int ccol = lane & 15, crow4 = (lane >> 4) << 2;
#pragma unroll
  for (int mr = 0; mr < 2; mr++) {
#pragma unroll
    for (int nc = 0; nc < 2; nc++) {
      int n = n0 + wc * 32 + nc * 16 + ccol;
      float bv = bias ? bias[(long)gw * b_gs + n] : 0.f;
#pragma unroll
      for (int r = 0; r < 4; r++) {
        int m = m0 + wr * 32 + mr * 16 + crow4 + r;
        float v = acc[mr][nc][r] + bv;
        if (ACT == 1) v = fmaxf(v, 0.f);
        if (OUTBF) ((__hip_bfloat16*)Cv)[(long)g * c_gs + (long)m * ldc + n] = __float2bfloat16(v);
        else       ((float*)Cv)[(long)g * c_gs + (long)m * ldc + n] = v;
      }
    }
  }
}

// ---------------- MFMA heads: kldg (p/q mean+std) ----------------
__global__ __launch_bounds__(256)
void k_heads_pq_mf(const __hip_bfloat16* __restrict__ LA, const __hip_bfloat16* __restrict__ LB,
                   const __hip_bfloat16* __restrict__ Wpm, const float* __restrict__ bpm,
                   const __hip_bfloat16* __restrict__ Wps, const float* __restrict__ bps,
                   const __hip_bfloat16* __restrict__ Wqm, const float* __restrict__ bqm,
                   const __hip_bfloat16* __restrict__ Wqs, const float* __restrict__ bqs,
                   const float* __restrict__ DP, float* __restrict__ PART, int t0) {
  const int g = blockIdx.z; const int tl = g >> 3, d = g & 7; const int t = t0 + tl;
  const int m0 = blockIdx.x * 64, n0 = blockIdx.y * 64;
  const int tid = threadIdx.x;
  const int wave = tid >> 6, lane = tid & 63;
  const int wr = wave >> 1, wc = wave & 1;
  __shared__ short As[64][40], W1s[64][40], W2s[64][40];
  f32x4 aPm[2][2], aPs[2][2], aQm[2][2], aQs[2][2];
#pragma unroll
  for (int a = 0; a < 2; a++)
#pragma unroll
    for (int b = 0; b < 2; b++) {
      aPm[a][b] = (f32x4)(0.f); aPs[a][b] = (f32x4)(0.f);
      aQm[a][b] = (f32x4)(0.f); aQs[a][b] = (f32x4)(0.f);
    }
  const int srow = tid >> 2, sks = (tid & 3) << 3;
  const int l15 = lane & 15, kq = (lane >> 4) << 3;
#pragma unroll
  for (int pass = 0; pass < 2; pass++) {
    const short* Ab = (const short*)(pass ? LB : LA) + (long)g * (BB * ZZ);
    const short* W1 = (const short*)(pass ? Wqm : Wpm) + (long)d * ZZ * ZZ;
    const short* W2 = (const short*)(pass ? Wqs : Wps) + (long)d * ZZ * ZZ;
    for (int kb = 0; kb < ZZ; kb += 32) {
      *(bf16x8*)&As[srow][sks]  = *(const bf16x8*)(Ab + (long)(m0 + srow) * ZZ + kb + sks);
      *(bf16x8*)&W1s[srow][sks] = *(const bf16x8*)(W1 + (long)(n0 + srow) * ZZ + kb + sks);
      *(bf16x8*)&W2s[srow][sks] = *(const bf16x8*)(W2 + (long)(n0 + srow) * ZZ + kb + sks);
      __syncthreads();
      bf16x8 a0 = *(const bf16x8*)&As[wr * 32 + l15][kq];
      bf16x8 a1 = *(const bf16x8*)&As[wr * 32 + 16 + l15][kq];
      bf16x8 m0f = *(const bf16x8*)&W1s[wc * 32 + l15][kq];
      bf16x8 m1f = *(const bf16x8*)&W1s[wc * 32 + 16 + l15][kq];
      bf16x8 s0f = *(const bf16x8*)&W2s[wc * 32 + l15][kq];
      bf16x8 s1f = *(const bf16x8*)&W2s[wc * 32 + 16 + l15][kq];
      if (pass == 0) {
        aPm[0][0] = __builtin_amdgcn_mfma_f32_16x16x32_bf16(a0, m0f, aPm[0][0], 0, 0, 0);
        aPm[0][1] = __builtin_amdgcn_mfma_f32_16x16x32_bf16(a0, m1f, aPm[0][1], 0, 0, 0);
        aPm[1][0] = __builtin_amdgcn_mfma_f32_16x16x32_bf16(a1, m0f, aPm[1][0], 0, 0, 0);
        aPm[1][1] = __builtin_amdgcn_mfma_f32_16x16x32_bf16(a1, m1f, aPm[1][1], 0, 0, 0);
        aPs[0][0] = __builtin_amdgcn_mfma_f32_16x16x32_bf16(a0, s0f, aPs[0][0], 0, 0, 0);
        aPs[0][1] = __builtin_amdgcn_mfma_f32_16x16x32_bf16(a0, s1f, aPs[0][1], 0, 0, 0);
        aPs[1][0] = __builtin_amdgcn_mfma_f32_16x16x32_bf16(a1, s0f, aPs[1][0], 0, 0, 0);
        aPs[1][1] = __builtin_amdgcn_mfma_f32_16x16x32_bf16(a1, s1f, aPs[1][1], 0, 0, 0);
      } else {
        aQm[0][0] = __builtin_amdgcn_mfma_f32_16x16x32_bf16(a0, m0f, aQm[0][0], 0, 0, 0);
        aQm[0][1] = __builtin_amdgcn_mfma_f32_16x16x32_bf16(a0, m1f, aQm[0][1], 0, 0, 0);
        aQm[1][0] = __builtin_amdgcn_mfma_f32_16x16x32_bf16(a1, m0f, aQm[1][0], 0, 0, 0);
        aQm[1][1] = __builtin_amdgcn_mfma_f32_16x16x32_bf16(a1, m1f, aQm[1][1], 0, 0, 0);
        aQs[0][0] = __builtin_amdgcn_mfma_f32_16x16x32_bf16(a0, s0f, aQs[0][0], 0, 0, 0);
        aQs[0][1] = __builtin_amdgcn_mfma_f32_16x16x32_bf16(a0, s1f, aQs[0][1], 0, 0, 0);
        aQs[1][0] = __builtin_amdgcn_mfma_f32_16x16x32_bf16(a1, s0f, aQs[1][0], 0, 0, 0);
        aQs[1][1] = __builtin_amdgcn_mfma_f32_16x16x32_bf16(a1, s1f, aQs[1][1], 0, 0, 0);
      }
      __syncthreads();
    }
  }
  // epilogue: kldg on fragments
  const int ccol = lane & 15, crow4 = (lane >> 4) << 2;
  float local = 0.f;
#pragma unroll
  for (int mr = 0; mr < 2; mr++) {
#pragma unroll
    for (int nc = 0; nc < 2; nc++) {
      int n = n0 + wc * 32 + nc * 16 + ccol;
      float bpmv = bpm[d * ZZ + n], bpsv = bps[d * ZZ + n];
      float bqmv = bqm[d * ZZ + n], bqsv = bqs[d * ZZ + n];
#pragma unroll
      for (int r = 0; r < 4; r++) {
        int m = m0 + wr * 32 + mr * 16 + crow4 + r;
        float w8 = DP[((long)(t + 1) * BB + m) * DD + d];
        float pm = aPm[mr][nc][r] + bpmv;
        float ps = softplusf_(aPs[mr][nc][r] + bpsv);
        float qm = aQm[mr][nc][r] + bqmv;
        float qs = softplusf_(aQs[mr][nc][r] + bqsv);
        float dm = qm - pm;
        local += 0.5f * w8 * (2.f * logf(ps / qs) + (qs * qs + dm * dm) / (ps * ps) - 1.f);
      }
    }
  }
  local = wave_sum(local);
  __shared__ float red[4];
  if ((tid & 63) == 0) red[wave] = local;
  __syncthreads();
  if (tid == 0) atomicAdd(&PART[((long)t * DD + d) * 4 + 0], red[0] + red[1] + red[2] + red[3]);
}

// ---------------- MFMA heads: nll (emission) + kldc ----------------
__global__ __launch_bounds__(256)
void k_heads_e_mf(const __hip_bfloat16* __restrict__ LA,
                  const __hip_bfloat16* __restrict__ Wem, const float* __restrict__ bem,
                  const __hip_bfloat16* __restrict__ Wes, const float* __restrict__ bes,
                  const float* __restrict__ yy, const float* __restrict__ DP,
                  const float* __restrict__ KCE, float* __restrict__ PART, int t0) {
  const int g = blockIdx.z; const int tl = g >> 3, d = g & 7; const int t = t0 + tl;
  const int m0 = blockIdx.x * 64, n0 = blockIdx.y * 64;
  const int tid = threadIdx.x;
  const int wave = tid >> 6, lane = tid & 63;
  const int wr = wave >> 1, wc = wave & 1;
  __shared__ short As[64][40], W1s[64][40], W2s[64][40];
  f32x4 aM[2][2], aS[2][2];
#pragma unroll
  for (int a = 0; a < 2; a++)
#pragma unroll
    for (int b = 0; b < 2; b++) { aM[a][b] = (f32x4)(0.f); aS[a][b] = (f32x4)(0.f); }
  const int srow = tid >> 2, sks = (tid & 3) << 3;
  const int l15 = lane & 15, kq = (lane >> 4) << 3;
  {
    const short* Ab = (const short*)LA + (long)g * (BB * ZZ);
    const short* W1 = (const short*)Wem + (long)d * YY * YY;
    const short* W2 = (const short*)Wes + (long)d * YY * YY;
    for (int kb = 0; kb < YY; kb += 32) {
      *(bf16x8*)&As[srow][sks]  = *(const bf16x8*)(Ab + (long)(m0 + srow) * YY + kb + sks);
      *(bf16x8*)&W1s[srow][sks] = *(const bf16x8*)(W1 + (long)(n0 + srow) * YY + kb + sks);
      *(bf16x8*)&W2s[srow][sks] = *(const bf16x8*)(W2 + (long)(n0 + srow) * YY + kb + sks);
      __syncthreads();
      bf16x8 a0 = *(const bf16x8*)&As[wr * 32 + l15][kq];
      bf16x8 a1 = *(const bf16x8*)&As[wr * 32 + 16 + l15][kq];
      bf16x8 m0f = *(const bf16x8*)&W1s[wc * 32 + l15][kq];
      bf16x8 m1f = *(const bf16x8*)&W1s[wc * 32 + 16 + l15][kq];
      bf16x8 s0f = *(const bf16x8*)&W2s[wc * 32 + l15][kq];
      bf16x8 s1f = *(const bf16x8*)&W2s[wc * 32 + 16 + l15][kq];
      aM[0][0] = __builtin_amdgcn_mfma_f32_16x16x32_bf16(a0, m0f, aM[0][0], 0, 0, 0);
      aM[0][1] = __builtin_amdgcn_mfma_f32_16x16x32_bf16(a0, m1f, aM[0][1], 0, 0, 0);
      aM[1][0] = __builtin_amdgcn_mfma_f32_16x16x32_bf16(a1, m0f, aM[1][0], 0, 0, 0);
      aM[1][1] = __builtin_amdgcn_mfma_f32_16x16x32_bf16(a1, m1f, aM[1][1], 0, 0, 0);
      aS[0][0] = __builtin_amdgcn_mfma_f32_16x16x32_bf16(a0, s0f, aS[0][0], 0, 0, 0);
      aS[0][1] = __builtin_amdgcn_mfma_f32_16x16x32_bf16(a0, s1f, aS[0][1], 0, 0, 0);
      aS[1][0] = __builtin_amdgcn_mfma_f32_16x16x32_bf16(a1, s0f, aS[1][0], 0, 0, 0);
      aS[1][1] = __builtin_amdgcn_mfma_f32_16x16x32_bf16(a1, s1f, aS[1][1], 0, 0, 0);
      __syncthreads();
    }
  }
  const int ccol = lane & 15, crow4 = (lane >> 4) << 2;
  float local = 0.f;
#pragma unroll
  for (int mr = 0; mr < 2; mr++) {
#pragma unroll
    for (int nc = 0; nc < 2; nc++) {
      int n = n0 + wc * 32 + nc * 16 + ccol;
      float bmv = bem[d * YY + n], bsv = bes[d * YY + n];
#pragma unroll
      for (int r = 0; r < 4; r++) {
        int m = m0 + wr * 32 + mr * 16 + crow4 + r;
        float w8 = DP[((long)(t + 1) * BB + m) * DD + d];
        float ym = aM[mr][nc][r] + bmv;
        float ys = softplusf_(aS[mr][nc][r] + bsv);
        float yv = yy[((long)t * BB + m) * YY + n];
        float rr = (yv - ym) / ys;
        local += w8 * 0.5f * (1.8378770664093453f + 2.f * logf(ys) + rr * rr);
      }
    }
  }
  local = wave_sum(local);
  __shared__ float red[4];
  if ((tid & 63) == 0) red[wave] = local;
  __syncthreads();
  if (tid == 0) atomicAdd(&PART[((long)t * DD + d) * 4 + 2], red[0] + red[1] + red[2] + red[3]);
  if (blockIdx.x == 0 && blockIdx.y == 0) {
    __syncthreads();
    float v = 0.f;
    if (tid < BB) v = KCE[((long)t * DD + d) * BB + tid] * DP[((long)t * BB + tid) * DD + d];
    v = wave_sum(v);
    if ((tid & 63) == 0) red[wave] = v;
    __syncthreads();
    if (tid == 0) atomicAdd(&PART[((long)t * DD + d) * 4 + 1], red[0] + red[1] + red[2] + red[3]);
  }
}

// ---------------- GRU step ----------------
__global__ __launch_bounds__(256)
void k_gru(const float* __restrict__ GI, const float* __restrict__ hprev,
           const float* __restrict__ Whh, const float* __restrict__ bhh,
           float* __restrict__ hout, __hip_bfloat16* __restrict__ houtB) {
  const int bt = blockIdx.x >> 5, jt = blockIdx.x & 31;
  const int b0 = bt * 16, j0 = jt * 16;
  const int tid = threadIdx.x;
  const int bi = tid >> 4, ji = tid & 15;
  __shared__ float ws[48][132];
  __shared__ float hs[16][132];
  float ar = 0.f, az = 0.f, an = 0.f;
  for (int kc = 0; kc < HH; kc += 128) {
    for (int idx = tid; idx < 48 * 32; idx += 256) {
      int r = idx >> 5, c4 = (idx & 31) << 2;
      int jr = r / 3, gr = r % 3;
      int grow = gr * HH + j0 + jr;
      *(float4*)&ws[r][c4] = *(const float4*)(Whh + (long)grow * HH + kc + c4);
    }
    for (int idx = tid; idx < 16 * 32; idx += 256) {
      int r = idx >> 5, c4 = (idx & 31) << 2;
      float4 v;
      if (hprev) v = *(const float4*)(hprev + (long)(b0 + r) * HH + kc + c4);
      else { v.x = v.y = v.z = v.w = 0.f; }
      *(float4*)&hs[r][c4] = v;
    }
    __syncthreads();
    const int r0 = ji * 3;
    for (int k4 = 0; k4 < 128; k4 += 4) {
      float4 hv = *(const float4*)&hs[bi][k4];
      float4 w0 = *(const float4*)&ws[r0 + 0][k4];
      float4 w1 = *(const float4*)&ws[r0 + 1][k4];
      float4 w2 = *(const float4*)&ws[r0 + 2][k4];
      ar = fmaf(hv.x, w0.x, fmaf(hv.y, w0.y, fmaf(hv.z, w0.z, fmaf(hv.w, w0.w, ar))));
      az = fmaf(hv.x, w1.x, fmaf(hv.y, w1.y, fmaf(hv.z, w1.z, fmaf(hv.w, w1.w, az))));
      an = fmaf(hv.x, w2.x, fmaf(hv.y, w2.y, fmaf(hv.z, w2.z, fmaf(hv.w, w2.w, an))));
    }
    __syncthreads();
  }
  int j = j0 + ji, b = b0 + bi;
  float gr_ = ar + bhh[j], gz = az + bhh[HH + j], gn = an + bhh[2 * HH + j];
  const float* gi = GI + (long)b * G3;
  float ir = gi[j], iz = gi[HH + j], inn = gi[2 * HH + j];
  float r = 1.f / (1.f + expf(-(ir + gr_)));
  float zg = 1.f / (1.f + expf(-(iz + gz)));
  float n = tanhf(inn + r * gn);
  float hp = hprev ? hprev[(long)b * HH + j] : 0.f;
  float hnew = (1.f - zg) * n + zg * hp;
  hout[(long)b * HH + j] = hnew;
  if (houtB) houtB[(long)b * HH + j] = __float2bfloat16(hnew);
}

// ---------------- d-posterior (all experts) + kldc_e, chunked (f32 h input) ----------------
__global__ __launch_bounds__(256)
void k_dpa(const float* __restrict__ Wdp, const float* __restrict__ bdp,
           const float* __restrict__ HF, const float* __restrict__ LOGT,
           float* __restrict__ DPA, float* __restrict__ KCE, int t0) {
  const int tl = blockIdx.x; const int t = t0 + tl;
  const int bq = blockIdx.y; const int bb0 = bq * 32;
  const int tid = threadIdx.x;
  const int wv = tid >> 6;
  const int di = tid & 63; const int dd = di >> 3, ii = di & 7;
  __shared__ float obs[32][132];
  float acc[8];
#pragma unroll
  for (int r = 0; r < 8; r++) acc[r] = 0.f;
  for (int kc = 0; kc < HH; kc += 128) {
    for (int idx = tid; idx < 32 * 32; idx += 256) {
      int r = idx >> 5, c4 = (idx & 31) << 2;
      *(float4*)&obs[r][c4] = *(const float4*)(HF + ((long)tl * BB + bb0 + r) * HH + kc + c4);
    }
    __syncthreads();
    const float* wr = Wdp + (long)di * HH + kc;
    for (int k = 0; k < 128; k += 4) {
      float4 w4 = *(const float4*)(wr + k);
#pragma unroll
      for (int r = 0; r < 8; r++) {
        int bl = r * 4 + wv;
        float4 o4 = *(const float4*)&obs[bl][k];
        acc[r] = fmaf(o4.x, w4.x, fmaf(o4.y, w4.y, fmaf(o4.z, w4.z, fmaf(o4.w, w4.w, acc[r]))));
      }
    }
    __syncthreads();
  }
  float bsum = bdp[di];
#pragma unroll
  for (int r = 0; r < 8; r++) {
    int bl = r * 4 + wv; int b = bb0 + bl;
    float v = acc[r] + bsum;
    float mx = v;
    for (int m = 1; m < 8; m <<= 1) mx = fmaxf(mx, __shfl_xor(mx, m, 64));
    float e = expf(v - mx);
    float sm = e;
    for (int m = 1; m < 8; m <<= 1) sm += __shfl_xor(sm, m, 64);
    float p = e / sm;
    DPA[(((long)t * BB + b) * DD + dd) * DD + ii] = p;
    float term = p * (logf(p + 1e-8f) - LOGT[dd * 8 + ii]);
    for (int m = 1; m < 8; m <<= 1) term += __shfl_xor(term, m, 64);
    if (ii == 0) KCE[((long)t * DD + dd) * BB + b] = term;
  }
}

// ---------------- sequential d-trajectory (tiny) ----------------
__global__ void k_dchain(const float* __restrict__ DPA, const uint2* __restrict__ K1s,
                         int* __restrict__ EIDX, float* __restrict__ DP) {
  int b = threadIdx.x;
  if (b >= BB) return;
  int e = EIDX[b];
  for (int t = 0; t < TT; t++) {
    uint2 k1 = K1s[t];
    const float* p = DPA + (((long)t * BB + b) * DD + e) * DD;
    float best = -1e30f; int bi = 0;
#pragma unroll
    for (int i = 0; i < DD; i++) {
      float pi = p[i];
      DP[((long)(t + 1) * BB + b) * DD + i] = pi;
      float sc = logf(pi) + gumbelf(rbits(k1, b * DD + i, BB * DD));
      if (sc > best) { best = sc; bi = i; }
    }
    e = bi;
    EIDX[(t + 1) * BB + b] = e;
  }
}

// ---------------- fused sequential scan step ----------------
__global__ __launch_bounds__(256)
void k_step(int t, const int* __restrict__ EIDX, const uint2* __restrict__ K2s,
            const __hip_bfloat16* __restrict__ OBPc,
            const float* __restrict__ Wq1, const float* __restrict__ bq1,
            const float* __restrict__ Wq2, const float* __restrict__ bq2,
            const float* __restrict__ Wqm, const float* __restrict__ bqm,
            const float* __restrict__ Wqs, const float* __restrict__ bqs,
            float* __restrict__ ZT) {
  const int d = blockIdx.x & 7, bt = blockIdx.x >> 3;
  const int b0 = bt * 8;
  const int tid = threadIdx.x;
  __shared__ float zt_s[256][8];
  __shared__ float h1t[256][8];
  __shared__ float h2t[256][8];
  __shared__ int en_s[8];
  for (int i = tid; i < 8 * 256; i += 256) {
    int bl = i >> 8, k = i & 255;
    zt_s[k][bl] = ZT[((long)t * BB + b0 + bl) * ZZ + k];
  }
  if (tid < 8) en_s[tid] = EIDX[(t + 1) * BB + b0 + tid];
  __syncthreads();
  // phase 1: h1 = relu(OBPc + Wq1z @ z_prev + bq1)
  {
    const int j = tid;
    const float* wr = Wq1 + ((long)(d * ZZ + j)) * 768 + 512;
    const __hip_bfloat16* obr = OBPc + (((long)d * TC + (t & (TC - 1))) * BB + b0) * ZZ + j;
    float bj = bq1[d * ZZ + j];
    float acc[8];
#pragma unroll
    for (int bl = 0; bl < 8; bl++) acc[bl] = bj + __bfloat162float(obr[bl * ZZ]);
    for (int k = 0; k < ZZ; k += 4) {
      float4 w4 = *(const float4*)(wr + k);
      float4 z0, z1;
      z0 = *(const float4*)&zt_s[k + 0][0]; z1 = *(const float4*)&zt_s[k + 0][4]; FMA8M(z0, z1, w4.x, acc);
      z0 = *(const float4*)&zt_s[k + 1][0]; z1 = *(const float4*)&zt_s[k + 1][4]; FMA8M(z0, z1, w4.y, acc);
      z0 = *(const float4*)&zt_s[k + 2][0]; z1 = *(const float4*)&zt_s[k + 2][4]; FMA8M(z0, z1, w4.z, acc);
      z0 = *(const float4*)&zt_s[k + 3][0]; z1 = *(const float4*)&zt_s[k + 3][4]; FMA8M(z0, z1, w4.w, acc);
    }
#pragma unroll
    for (int bl = 0; bl < 8; bl++) h1t[j][bl] = fmaxf(acc[bl], 0.f);
  }
  __syncthreads();
  // phase 2: h2 = relu(Wq2 @ h1 + bq2)
  {
    const int j = tid;
    const float* wr = Wq2 + ((long)(d * ZZ + j)) * ZZ;
    float bj = bq2[d * ZZ + j];
    float acc[8];
#pragma unroll
    for (int bl = 0; bl < 8; bl++) acc[bl] = bj;
    for (int k = 0; k < ZZ; k += 4) {
      float4 w4 = *(const float4*)(wr + k);
      float4 z0, z1;
      z0 = *(const float4*)&h1t[k + 0][0]; z1 = *(const float4*)&h1t[k + 0][4]; FMA8M(z0, z1, w4.x, acc);
      z0 = *(const float4*)&h1t[k + 1][0]; z1 = *(const float4*)&h1t[k + 1][4]; FMA8M(z0, z1, w4.y, acc);
      z0 = *(const float4*)&h1t[k + 2][0]; z1 = *(const float4*)&h1t[k + 2][4]; FMA8M(z0, z1, w4.z, acc);
      z0 = *(const float4*)&h1t[k + 3][0]; z1 = *(const float4*)&h1t[k + 3][4]; FMA8M(z0, z1, w4.w, acc);
    }
#pragma unroll
    for (int bl = 0; bl < 8; bl++) h2t[j][bl] = fmaxf(acc[bl], 0.f);
  }
  __syncthreads();
  // phase 3: heads qm / qs(raw)
  float qm[8], qs[8];
  {
    const int j = tid;
    const float* wm = Wqm + ((long)(d * ZZ + j)) * ZZ;
    const float* wsd = Wqs + ((long)(d * ZZ + j)) * ZZ;
    float bm_ = bqm[d * ZZ + j], bs__ = bqs[d * ZZ + j];
#pragma unroll
    for (int bl = 0; bl < 8; bl++) { qm[bl] = bm_; qs[bl] = bs__; }
    for (int k = 0; k < ZZ; k += 4) {
      float4 wm4 = *(const float4*)(wm + k);
      float4 ws4 = *(const float4*)(wsd + k);
#pragma unroll
      for (int kk = 0; kk < 4; kk++) {
        float wmv = kk == 0 ? wm4.x : kk == 1 ? wm4.y : kk == 2 ? wm4.z : wm4.w;
        float wsv = kk == 0 ? ws4.x : kk == 1 ? ws4.y : kk == 2 ? ws4.z : ws4.w;
        float4 h0 = *(const float4*)&h2t[k + kk][0];
        float4 h1v = *(const float4*)&h2t[k + kk][4];
        FMA8M(h0, h1v, wmv, qm);
        FMA8M(h0, h1v, wsv, qs);
      }
    }
  }
  // phase 4: z sample (only block with matching expert writes)
#pragma unroll
  for (int bl = 0; bl < 8; bl++) {
    if (en_s[bl] == d) {
      int b = b0 + bl;
      float eps = normalf(rbits(K2s[t], b * ZZ + tid, BB * ZZ));
      ZT[((long)(t + 1) * BB + b) * ZZ + tid] = qm[bl] + softplusf_(qs[bl]) * eps;
    }
  }
}

__global__ void k_fin(const float* __restrict__ PART, float* __restrict__ out) {
  int tid = threadIdx.x;
  float s0 = 0.f, s1 = 0.f, s2 = 0.f;
  for (int i = tid; i < TT * DD; i += 256) {
    s0 += PART[i * 4 + 0]; s1 += PART[i * 4 + 1]; s2 += PART[i * 4 + 2];
  }
  s0 = wave_sum(s0); s1 = wave_sum(s1); s2 = wave_sum(s2);
  __shared__ float r0[4], r1[4], r2[4];
  int wid = tid >> 6;
  if ((tid & 63) == 0) { r0[wid] = s0; r1[wid] = s1; r2[wid] = s2; }
  __syncthreads();
  if (tid == 0) {
    out[0] = r0[0] + r0[1] + r0[2] + r0[3];
    out[1] = r1[0] + r1[1] + r1[2] + r1[3];
    out[2] = r2[0] + r2[1] + r2[2] + r2[3];
  }
}

// ---------------- host launcher ----------------
extern "C" void kernel_launch(void* const* d_in, const int* in_sizes, int n_in,
                              void* d_out, int out_size, void* d_ws, size_t ws_size,
                              hipStream_t stream) {
  (void)in_sizes; (void)n_in; (void)out_size;
  const float* x      = (const float*)d_in[0];
  const float* y      = (const float*)d_in[1];
  const float* Wdpr   = (const float*)d_in[2];
  const float* bdpr   = (const float*)d_in[3];
  const float* Wdp    = (const float*)d_in[4];
  const float* bdp    = (const float*)d_in[5];
  const float* Wq1    = (const float*)d_in[6];
  const float* bq1    = (const float*)d_in[7];
  const float* Wq2    = (const float*)d_in[8];
  const float* bq2    = (const float*)d_in[9];
  const float* Wqm    = (const float*)d_in[10];
  const float* bqm    = (const float*)d_in[11];
  const float* Wqs    = (const float*)d_in[12];
  const float* bqs    = (const float*)d_in[13];
  const float* Wp1    = (const float*)d_in[14];
  const float* bp1    = (const float*)d_in[15];
  const float* Wp2    = (const float*)d_in[16];
  const float* bp2    = (const float*)d_in[17];
  const float* Wpm    = (const float*)d_in[18];
  const float* bpm    = (const float*)d_in[19];
  const float* Wps    = (const float*)d_in[20];
  const float* bps    = (const float*)d_in[21];
  const float* We1    = (const float*)d_in[22];
  const float* be1    = (const float*)d_in[23];
  const float* We2    = (const float*)d_in[24];
  const float* be2    = (const float*)d_in[25];
  const float* Wem    = (const float*)d_in[26];
  const float* bem    = (const float*)d_in[27];
  const float* Wes    = (const float*)d_in[28];
  const float* bes    = (const float*)d_in[29];
  const float* Wih_f  = (const float*)d_in[30];
  const float* Whh_f  = (const float*)d_in[31];
  const float* bih_f  = (const float*)d_in[32];
  const float* bhh_f  = (const float*)d_in[33];
  const float* Wih_b  = (const float*)d_in[34];
  const float* Whh_b  = (const float*)d_in[35];
  const float* bih_b  = (const float*)d_in[36];
  const float* bhh_b  = (const float*)d_in[37];

  char* base = (char*)d_ws;
  size_t off = 0;
  auto alloc = [&](size_t bytes) -> char* {
    char* p = base + off;
    off += (bytes + 1023) & ~(size_t)1023;
    return p;
  };
  float* LOGT = (float*)alloc(64 * 4);
  uint2* KEYS = (uint2*)alloc(TT * 8);
  uint2* K1s  = (uint2*)alloc(TT * 8);
  uint2* K2s  = (uint2*)alloc(TT * 8);
  int*   EIDX = (int*)alloc((size_t)(TT + 1) * BB * 4);
  float* DP   = (float*)alloc((size_t)(TT + 1) * BB * DD * 4);
  float* DPA  = (float*)alloc((size_t)TT * BB * DD * DD * 4);
  float* KCE  = (float*)alloc((size_t)TT * DD * BB * 4);
  float* ZT   = (float*)alloc((size_t)(TT + 1) * BB * ZZ * 4);
  float* PART = (float*)alloc((size_t)TT * DD * 4 * 4);
  float* OF   = (float*)alloc((size_t)TT * BB * HH * 4);          // f32 (d-path fidelity + loss)
  __hip_bfloat16* OB = (__hip_bfloat16*)alloc((size_t)TT * BB * HH * 2);  // bf16 (z-path/loss only)
  float* HROLL = (float*)alloc((size_t)TC * BB * HH * 4);         // f32 rolling backward h
  char*  SH   = alloc((size_t)TC * BB * G3 * 4);                  // 25.2MB shared region
  // bf16 weight copies (smooth path only)
  const size_t SL1 = (size_t)DD * ZZ * 768;   // 1,572,864 elems
  const size_t SL2 = (size_t)DD * ZZ * ZZ;    // 524,288 elems
  __hip_bfloat16* WB = (__hip_bfloat16*)alloc((3 * SL1 + 9 * SL2) * 2);  // 18.9MB
  __hip_bfloat16* bWq1 = WB;
  __hip_bfloat16* bWp1 = bWq1 + SL1;
  __hip_bfloat16* bWe1 = bWp1 + SL1;
  __hip_bfloat16* bWq2 = bWe1 + SL1;
  __hip_bfloat16* bWp2 = bWq2 + SL2;
  __hip_bfloat16* bWe2 = bWp2 + SL2;
  __hip_bfloat16* bWqm = bWe2 + SL2;
  __hip_bfloat16* bWqs = bWqm + SL2;
  __hip_bfloat16* bWpm = bWqs + SL2;
  __hip_bfloat16* bWps = bWpm + SL2;
  __hip_bfloat16* bWem = bWps + SL2;
  __hip_bfloat16* bWes = bWem + SL2;

  float* GIc  = (float*)SH;
  __hip_bfloat16* OBPc = (__hip_bfloat16*)SH;
  __hip_bfloat16* LH1b  = (__hip_bfloat16*)SH;
  __hip_bfloat16* LH2Ab = LH1b + (size_t)CH * DD * BB * ZZ;
  __hip_bfloat16* LH2Bb = LH2Ab + (size_t)CH * DD * BB * ZZ;

  if (ws_size < off) {   // workspace too small: emit sentinel instead of faulting
    k_sentinel<<<1, 64, 0, stream>>>((float*)d_out);
    return;
  }

  hipMemsetAsync(PART, 0, (size_t)TT * DD * 4 * 4, stream);
  k_init1<<<1, 256, 0, stream>>>(Wdpr, bdpr, LOGT, KEYS, K1s, K2s);
  k_init2<<<33, 256, 0, stream>>>(EIDX, DP, ZT);

  // weight conversions (12 small launches)
  auto cvt = [&](const float* s, __hip_bfloat16* dst, size_t n) {
    int n4 = (int)(n >> 2);
    int grid = (n4 + 255) / 256; if (grid > 1024) grid = 1024;
    k_cvt<<<grid, 256, 0, stream>>>(s, dst, n4);
  };
  cvt(Wq1, bWq1, SL1); cvt(Wp1, bWp1, SL1); cvt(We1, bWe1, SL1);
  cvt(Wq2, bWq2, SL2); cvt(Wp2, bWp2, SL2); cvt(We2, bWe2, SL2);
  cvt(Wqm, bWqm, SL2); cvt(Wqs, bWqs, SL2);
  cvt(Wpm, bWpm, SL2); cvt(Wps, bWps, SL2);
  cvt(Wem, bWem, SL2); cvt(Wes, bWes, SL2);

  const long BH = (long)BB * HH, BZ = (long)BB * ZZ, BG = (long)BB * G3;

  // forward GRU, chunked input projection (f32 — feeds discrete d-path)
  for (int c = 0; c < TT / TC; c++) {
    int t0 = c * TC;
    gemm2seg<0, 0><<<dim3(64, 24, 1), 256, 0, stream>>>(
        x + (long)t0 * BB * XX, 0, XX, XX, nullptr, 0, 4, 0,
        Wih_f, 0, XX, 0, bih_f, 0, GIc, 0, G3, 1);
    for (int tl = 0; tl < TC; tl++) {
      int t = t0 + tl;
      k_gru<<<256, 256, 0, stream>>>(GIc + (long)tl * BG,
                                     t ? (OF + (long)(t - 1) * BH) : nullptr,
                                     Whh_f, bhh_f, OF + (long)t * BH, nullptr);
    }
  }
  // backward GRU (reversed time), chunked; f32 h in HROLL, bf16 persist in OB
  for (int c = TT / TC - 1; c >= 0; c--) {
    int t0 = c * TC;
    gemm2seg<0, 0><<<dim3(64, 24, 1), 256, 0, stream>>>(
        y + (long)t0 * BB * YY, 0, YY, YY, OF + (long)t0 * BH, 0, HH, HH,
        Wih_b, 0, 768, 0, bih_b, 0, GIc, 0, G3, 1);
    for (int tl = TC - 1; tl >= 0; tl--) {
      int t = t0 + tl;
      k_gru<<<256, 256, 0, stream>>>(GIc + (long)tl * BG,
                                     (t == TT - 1) ? nullptr : (HROLL + (long)((t + 1) & (TC - 1)) * BH),
                                     Whh_b, bhh_b, HROLL + (long)(t & (TC - 1)) * BH, OB + (long)t * BH);
    }
    k_dpa<<<dim3(TC, 4), 256, 0, stream>>>(Wdp, bdp, HROLL, LOGT, DPA, KCE, t0);
  }
  // sequential d-trajectory
  k_dchain<<<1, 128, 0, stream>>>(DPA, K1s, EIDX, DP);
  // z-scan, chunked OBP hoist (MFMA, bf16 weights)
  for (int c = 0; c < TT / TC; c++) {
    int t0 = c * TC;
    gemmMF<0, 1, 1><<<dim3(64, 4, 8), 256, 0, stream>>>(
        OB + (long)t0 * BH, 0, HH, HH, nullptr, 0, 4, 0,
        bWq1, (long)ZZ * 768, 768, 0, nullptr, 0, OBPc, (long)TC * BB * ZZ, ZZ, 8);
    for (int tl = 0; tl < TC; tl++) {
      k_step<<<128, 256, 0, stream>>>(t0 + tl, EIDX, K2s, OBPc,
                                      Wq1, bq1, Wq2, bq2, Wqm, bqm, Wqs, bqs, ZT);
    }
  }
  // parallel loss pass, chunked over t (full MFMA: MLPs + heads)
  for (int c = 0; c < TT / CH; c++) {
    int t0 = c * CH;
    dim3 gl(2, 4, CH * DD);
    // p branch
    gemmMF<1, 1, 0><<<gl, 256, 0, stream>>>(
        OF + (long)t0 * BH, BH, HH, HH, ZT + (long)t0 * BZ, BZ, ZZ, ZZ,
        bWp1, (long)ZZ * 768, 768, 0, bp1, ZZ, LH1b, BZ, ZZ, 8);
    gemmMF<1, 1, 1><<<gl, 256, 0, stream>>>(
        LH1b, BZ, ZZ, ZZ, nullptr, 0, 4, 0,
        bWp2, (long)ZZ * ZZ, ZZ, 0, bp2, ZZ, LH2Ab, BZ, ZZ, 1);
    // q branch (A0 = OB bf16, K=768)
    gemmMF<1, 1, 1><<<gl, 256, 0, stream>>>(
        OB + (long)t0 * BH, BH, HH, HH, ZT + (long)t0 * BZ, BZ, ZZ, ZZ,
        bWq1, (long)ZZ * 768, 768, 0, bq1, ZZ, LH1b, BZ, ZZ, 8);
    gemmMF<1, 1, 1><<<gl, 256, 0, stream>>>(
        LH1b, BZ, ZZ, ZZ, nullptr, 0, 4, 0,
        bWq2, (long)ZZ * ZZ, ZZ, 0, bq2, ZZ, LH2Bb, BZ, ZZ, 1);
    k_heads_pq_mf<<<gl, 256, 0, stream>>>(LH2Ab, LH2Bb, bWpm, bpm, bWps, bps,
                                          bWqm, bqm, bWqs, bqs, DP, PART, t0);
    // e branch
    gemmMF<1, 1, 0><<<gl, 256, 0, stream>>>(
        OF + (long)t0 * BH, BH, HH, HH, ZT + (long)(t0 + 1) * BZ, BZ, ZZ, ZZ,
        bWe1, (long)YY * 768, 768, 0, be1, YY, LH1b, BZ, ZZ, 8);
    gemmMF<1, 1, 1><<<gl, 256, 0, stream>>>(
        LH1b, BZ, ZZ, ZZ, nullptr, 0, 4, 0,
        bWe2, (long)YY * YY, YY, 0, be2, YY, LH2Ab, BZ, ZZ, 1);
    k_heads_e_mf<<<gl, 256, 0, stream>>>(LH2Ab, bWem, bem, bWes, bes, y, DP, KCE, PART, t0);
  }
  k_fin<<<1, 256, 0, stream>>>(PART, (float*)d_out);
}